// Round 5
// baseline (276.507 us; speedup 1.0000x reference)
//
#include <hip/hip_runtime.h>

#define DIM 512
#define SEQ 2048
#define MROWS 8192

typedef short short8 __attribute__((ext_vector_type(8)));
typedef float floatx4 __attribute__((ext_vector_type(4)));

__device__ __forceinline__ ushort f2bf(float f) {
  union { float f; unsigned u; } v; v.f = f;
  unsigned r = v.u + 0x7fff + ((v.u >> 16) & 1);
  return (ushort)(r >> 16);
}
__device__ __forceinline__ float bf2f(ushort u) {
  union { unsigned u; float f; } v; v.u = ((unsigned)u) << 16;
  return v.f;
}

// ---------------------------------------------------------------------------
// prep (blocks 0..4095): vis->bf16, xp = x + concat(emb1[c1],emb2[c2]) -> bf16
// wtrans (blocks 4096..4415): Wt[n][k] = W[k][n] bf16.
// wq pre-scaled by 0.125*log2(e): QK^T then yields S*log2e, so softmax uses
// a bare v_exp_f32 (exp2) with no per-element multiply. exp2(s*log2e)=e^s.
// ---------------------------------------------------------------------------
__global__ __launch_bounds__(256) void prep_wtrans_kernel(
    const float* __restrict__ x, const float* __restrict__ vis,
    const int* __restrict__ c1, const int* __restrict__ c2,
    const float* __restrict__ e1, const float* __restrict__ e2,
    const float* __restrict__ wq, const float* __restrict__ wk,
    const float* __restrict__ wv, const float* __restrict__ w1,
    const float* __restrict__ w2,
    ushort* __restrict__ xp_bf, ushort* __restrict__ vis_bf,
    ushort* __restrict__ wt_qkv, ushort* __restrict__ wt1,
    ushort* __restrict__ wt2) {
  __shared__ float Ls[64 * 65];
  if (blockIdx.x < 4096) {
    int gid = blockIdx.x * 256 + threadIdx.x;
    int row = gid >> 7;
    int col = (gid & 127) * 4;
    float4 vv = *(const float4*)(vis + (size_t)row * 512 + col);
    ushort4 vb; vb.x = f2bf(vv.x); vb.y = f2bf(vv.y); vb.z = f2bf(vv.z); vb.w = f2bf(vv.w);
    *(ushort4*)(vis_bf + (size_t)row * 512 + col) = vb;
    float4 p;
    if (col < 256) p = *(const float4*)(e1 + (size_t)c1[row] * 256 + col);
    else           p = *(const float4*)(e2 + (size_t)c2[row] * 256 + col - 256);
    float4 xv = *(const float4*)(x + (size_t)row * 512 + col);
    ushort4 xb; xb.x = f2bf(xv.x + p.x); xb.y = f2bf(xv.y + p.y);
    xb.z = f2bf(xv.z + p.z); xb.w = f2bf(xv.w + p.w);
    *(ushort4*)(xp_bf + (size_t)row * 512 + col) = xb;
  } else {
    int bid = blockIdx.x - 4096;
    int mid = bid >> 6;
    int tile = bid & 63;
    int k0 = (tile >> 3) * 64, n0 = (tile & 7) * 64;
    const float* W = mid == 0 ? wq : mid == 1 ? wk : mid == 2 ? wv : mid == 3 ? w1 : w2;
    ushort* outp = mid < 3 ? (wt_qkv + (size_t)mid * 512 * 512) : (mid == 3 ? wt1 : wt2);
    float scale = (mid == 0) ? 0.125f * 1.44269504f : 1.0f;
    int r = threadIdx.x >> 4, c4 = (threadIdx.x & 15) * 4;
#pragma unroll
    for (int i = 0; i < 4; i++) {
      int row = i * 16 + r;
      float4 wv4 = *(const float4*)(W + (size_t)(k0 + row) * 512 + n0 + c4);
      Ls[row * 65 + c4 + 0] = wv4.x * scale;
      Ls[row * 65 + c4 + 1] = wv4.y * scale;
      Ls[row * 65 + c4 + 2] = wv4.z * scale;
      Ls[row * 65 + c4 + 3] = wv4.w * scale;
    }
    __syncthreads();
    int n = threadIdx.x >> 2, kc = (threadIdx.x & 3) * 16;
    ushort pk[16];
#pragma unroll
    for (int i = 0; i < 16; i++) pk[i] = f2bf(Ls[(kc + i) * 65 + n]);
    ushort* op = outp + (size_t)(n0 + n) * 512 + k0 + kc;
    *(uint4*)op = *(uint4*)pk;
    *(uint4*)(op + 8) = *(uint4*)(pk + 8);
  }
}

// ---------------------------------------------------------------------------
// bf16 MFMA GEMM, 64x128 (MxN) tile, BK=64, XOR-swizzled LDS, bias (+leaky)
// A/B staging via global_load_lds (16B DMA, linear LDS dest, pre-swizzled
// per-lane global source). grid (nchunks, 128). seg selects A/bias/out.
// ---------------------------------------------------------------------------
template <bool LEAKY>
__global__ __launch_bounds__(256, 4) void gemm_mfma(
    const ushort* __restrict__ A01, const ushort* __restrict__ A2,
    const ushort* __restrict__ Wt,
    const float* __restrict__ bias0, const float* __restrict__ bias1,
    const float* __restrict__ bias2,
    ushort* __restrict__ out0, ushort* __restrict__ out1,
    ushort* __restrict__ out2, float s0scale) {
  __shared__ __align__(16) ushort Sm[12288];  // As 64x64 | Bs 128x64 = 24 KB
  ushort* As = Sm;
  ushort* Bs = Sm + 4096;
  int t = threadIdx.x;
  int seg = blockIdx.x >> 2;
  int nloc0 = (blockIdx.x & 3) * 128;
  int n0w = blockIdx.x * 128;
  int m0 = blockIdx.y * 64;
  const ushort* A = (seg < 2) ? A01 : A2;
  const float* bias = seg == 0 ? bias0 : seg == 1 ? bias1 : bias2;
  ushort* out = seg == 0 ? out0 : seg == 1 ? out1 : out2;
  float bscale = seg == 0 ? s0scale : 1.0f;

  int w = t >> 6, lane = t & 63;
  int wm = (w & 1) * 32, wn = (w >> 1) * 64;
  int quad = lane >> 4, lcol = lane & 15;
  int l8g = lane >> 3, l7g = lane & 7;
  int gchs = (l7g ^ l8g) * 8;  // pre-swizzled source chunk (ushorts)

  floatx4 acc[2][4] = {};

  for (int k0 = 0; k0 < 512; k0 += 64) {
    __syncthreads();
    // A tile: 16 rows/wave via 2 DMA instrs (8 rows x 64 ushorts each)
#pragma unroll
    for (int i = 0; i < 2; i++) {
      int r0 = w * 16 + i * 8;
      __builtin_amdgcn_global_load_lds(
          (const __attribute__((address_space(1))) unsigned*)(
              A + (size_t)(m0 + r0 + l8g) * 512 + k0 + gchs),
          (__attribute__((address_space(3))) unsigned*)(&As[r0 * 64]),
          16, 0, 0);
    }
    // B tile: 32 rows/wave via 4 DMA instrs
#pragma unroll
    for (int i = 0; i < 4; i++) {
      int r0 = w * 32 + i * 8;
      __builtin_amdgcn_global_load_lds(
          (const __attribute__((address_space(1))) unsigned*)(
              Wt + (size_t)(n0w + r0 + l8g) * 512 + k0 + gchs),
          (__attribute__((address_space(3))) unsigned*)(&Bs[r0 * 64]),
          16, 0, 0);
    }
    asm volatile("s_waitcnt vmcnt(0)" ::: "memory");
    __syncthreads();
#pragma unroll
    for (int kc = 0; kc < 2; kc++) {
      int pch = ((kc * 4 + quad) ^ (lcol & 7)) * 8;
      short8 af[2], bfr[4];
#pragma unroll
      for (int i = 0; i < 2; i++)
        af[i] = *(const short8*)(&As[(wm + i * 16 + lcol) * 64 + pch]);
#pragma unroll
      for (int i = 0; i < 4; i++)
        bfr[i] = *(const short8*)(&Bs[(wn + i * 16 + lcol) * 64 + pch]);
#pragma unroll
      for (int mt = 0; mt < 2; mt++)
#pragma unroll
        for (int nt = 0; nt < 4; nt++)
          acc[mt][nt] = __builtin_amdgcn_mfma_f32_16x16x32_bf16(
              af[mt], bfr[nt], acc[mt][nt], 0, 0, 0);
    }
  }

  // epilogue: wave-private LDS transpose -> coalesced 16B bf16 stores
  __syncthreads();
  float* Ls = (float*)Sm + w * 1088;  // 16x68 f32 per wave
  int rr = lane >> 2, cc = (lane & 3) * 16;
#pragma unroll
  for (int mt = 0; mt < 2; mt++) {
#pragma unroll
    for (int nt = 0; nt < 4; nt++) {
      float bv = bias[nloc0 + wn + nt * 16 + lcol] * bscale;
#pragma unroll
      for (int r = 0; r < 4; r++) {
        float vv = acc[mt][nt][r] + bv;
        if (LEAKY) vv = vv >= 0.f ? vv : 0.2f * vv;
        Ls[(quad * 4 + r) * 68 + nt * 16 + lcol] = vv;
      }
    }
    asm volatile("s_waitcnt lgkmcnt(0)" ::: "memory");
    ushort pk[16];
#pragma unroll
    for (int i = 0; i < 16; i += 4) {
      float4 fv = *(const float4*)(&Ls[rr * 68 + cc + i]);
      pk[i] = f2bf(fv.x); pk[i + 1] = f2bf(fv.y);
      pk[i + 2] = f2bf(fv.z); pk[i + 3] = f2bf(fv.w);
    }
    ushort* op = out + (size_t)(m0 + wm + mt * 16 + rr) * 512 + nloc0 + wn + cc;
    *(uint4*)op = *(uint4*)pk;
    *(uint4*)(op + 8) = *(uint4*)(pk + 8);
    asm volatile("s_waitcnt lgkmcnt(0)" ::: "memory");
  }
}

// ---------------------------------------------------------------------------
// MFMA flash attention v2.1: verified v2 layout math; two latency fixes:
// (1) vf (V-fragment) ds_reads hoisted BEFORE the softmax VALU block -- they
//     depend only on last-iter's Vt buffer, not on P; previously trapped
//     behind the lgkmcnt(0) memory clobber, fully exposed (~16 b128 loads).
// (2) softmax uses exp2f (bare v_exp_f32): log2e folded into wq pre-scale.
// sched_barrier(0) after each asm lgkmcnt (rule-18 hoist protection).
// LDS 80 KB -> 2 blocks/CU (grid 512 = exact residency).
// ---------------------------------------------------------------------------
__global__ __launch_bounds__(256, 2) void attn_mfma_kernel(
    const ushort* __restrict__ q, const ushort* __restrict__ k,
    const ushort* __restrict__ v, ushort* __restrict__ out) {
  __shared__ __align__(16) ushort Ks[2][128 * 64];   // 2 x 16 KB, dbuf
  __shared__ __align__(16) ushort Vt[2][64 * 128];   // 2 x 16 KB, dbuf
  __shared__ __align__(16) unsigned Pp[4096];        // 16 KB, wave-private P^T
  int t = threadIdx.x;
  int blk = blockIdx.x;
  // XCD-chunked swizzle (bijective bit-rotate on 512 blocks):
  // 64 consecutive logical blocks (4 heads) per XCD L2
  blk = ((blk & 7) << 6) | (blk >> 3);
  int qt = blk & 15, h = (blk >> 4) & 7, b = blk >> 7;
  int wave = t >> 6, lane = t & 63, quad = lane >> 4, lcol = lane & 15;
  int q0 = qt * 128 + wave * 32;
  const size_t base = (size_t)b * SEQ * 512 + h * 64;

  short8 qf[2][2];
#pragma unroll
  for (int qm = 0; qm < 2; qm++)
#pragma unroll
    for (int kc = 0; kc < 2; kc++)
      qf[qm][kc] = *(const short8*)(
          q + base + (size_t)(q0 + qm * 16 + lcol) * 512 + kc * 32 + quad * 8);

  floatx4 O[2][4] = {};
  float lsum[2] = {0.f, 0.f};

  unsigned* Ppw = Pp + wave * 1024;
  int pl = t & 63, dg = t >> 6;           // V staging: rows 2pl,2pl+1 dims dg*16+
  int l8 = lane >> 3, l7 = lane & 7;
  int kchs = (l7 ^ l8) * 8;               // pre-swizzled K source chunk (ushorts)
  const ushort* vbase = v + base + (size_t)(2 * pl) * 512 + dg * 16;

  uint4 va[2], vb[2];

  // ---- prologue: stage tile 0 ----
#pragma unroll
  for (int j = 0; j < 4; j++) {
    const ushort* gp = k + base + (size_t)((wave * 4 + j) * 8 + l8) * 512 + kchs;
    __builtin_amdgcn_global_load_lds(
        (const __attribute__((address_space(1))) unsigned*)gp,
        (__attribute__((address_space(3))) unsigned*)(&Ks[0][(wave * 4 + j) * 512]),
        16, 0, 0);
  }
  va[0] = *(const uint4*)(vbase);       va[1] = *(const uint4*)(vbase + 8);
  vb[0] = *(const uint4*)(vbase + 512); vb[1] = *(const uint4*)(vbase + 520);
  {
    const ushort* a0 = (const ushort*)va;
    const ushort* a1 = (const ushort*)vb;
#pragma unroll
    for (int i = 0; i < 16; i++) {
      int dim = dg * 16 + i;
      unsigned pack = (unsigned)a0[i] | ((unsigned)a1[i] << 16);
      int pch = (pl >> 2) ^ (dim & 7);
      *(unsigned*)(&Vt[0][dim * 128 + pch * 8 + (pl & 3) * 2]) = pack;
    }
  }
  __syncthreads();

  int cb = 0;
  for (int it = 0; it < 16; it++) {
    // ---- issue next tile's loads early (T14): K via DMA, V into regs ----
    if (it < 15) {
      int ktn = (it + 1) * 128;
#pragma unroll
      for (int j = 0; j < 4; j++) {
        const ushort* gp =
            k + base + (size_t)(ktn + (wave * 4 + j) * 8 + l8) * 512 + kchs;
        __builtin_amdgcn_global_load_lds(
            (const __attribute__((address_space(1))) unsigned*)gp,
            (__attribute__((address_space(3))) unsigned*)(
                &Ks[cb ^ 1][(wave * 4 + j) * 512]),
            16, 0, 0);
      }
      const ushort* vr = vbase + (size_t)ktn * 512;
      va[0] = *(const uint4*)(vr);       va[1] = *(const uint4*)(vr + 8);
      vb[0] = *(const uint4*)(vr + 512); vb[1] = *(const uint4*)(vr + 520);
    }

    const ushort* Ksb = Ks[cb];
    const ushort* Vtb = Vt[cb];
#pragma unroll
    for (int half = 0; half < 2; half++) {
      // hoist the 8 K fragments for this 64-key half (reused across qm)
      short8 kf[2][4];
#pragma unroll
      for (int kc = 0; kc < 2; kc++) {
        int pch = ((kc * 4 + quad) ^ (lcol & 7)) * 8;
#pragma unroll
        for (int jt = 0; jt < 4; jt++)
          kf[kc][jt] =
              *(const short8*)(&Ksb[((half * 4 + jt) * 16 + lcol) * 64 + pch]);
      }
      // hoist V fragments too: independent of P, latency hides under softmax
      short8 vf[2][4];
#pragma unroll
      for (int kc = 0; kc < 2; kc++) {
        int ch = half * 8 + kc * 4 + quad;
#pragma unroll
        for (int nt = 0; nt < 4; nt++)
          vf[kc][nt] = *(const short8*)(
              &Vtb[(nt * 16 + lcol) * 128 + ((ch ^ (lcol & 7)) * 8)]);
      }
#pragma unroll
      for (int qm = 0; qm < 2; qm++) {
        floatx4 S[4] = {};
        __builtin_amdgcn_s_setprio(1);
#pragma unroll
        for (int kc = 0; kc < 2; kc++)
#pragma unroll
          for (int jt = 0; jt < 4; jt++)
            S[jt] = __builtin_amdgcn_mfma_f32_16x16x32_bf16(
                kf[kc][jt], qf[qm][kc], S[jt], 0, 0, 0);
        __builtin_amdgcn_s_setprio(0);
        // S^T: col=lane&15=q, row=quad*4+r=key (within 16-key tile jt)
        // S is pre-scaled by log2e -> exp2f is a bare v_exp_f32
#pragma unroll
        for (int jt = 0; jt < 4; jt++) {
          float e0 = exp2f(S[jt][0]);
          float e1 = exp2f(S[jt][1]);
          float e2 = exp2f(S[jt][2]);
          float e3 = exp2f(S[jt][3]);
          lsum[qm] += (e0 + e1) + (e2 + e3);
          unsigned p0, p1;
          asm("v_cvt_pk_bf16_f32 %0, %1, %2" : "=v"(p0) : "v"(e0), "v"(e1));
          asm("v_cvt_pk_bf16_f32 %0, %1, %2" : "=v"(p1) : "v"(e2), "v"(e3));
          // pair index p0base = jt*8 + quad*2 ; chunk-of-4 XOR swizzle on lcol
          int c0 = 2 * jt + (quad >> 1);
          uint2 pk2; pk2.x = p0; pk2.y = p1;
          *(uint2*)(Ppw + qm * 512 + lcol * 32 + ((c0 ^ (lcol & 7)) << 2) +
                    (quad & 1) * 2) = pk2;
        }
      }
      asm volatile("s_waitcnt lgkmcnt(0)" ::: "memory");
      __builtin_amdgcn_sched_barrier(0);
      // PV: O^T[d][q] += V^T * P^T  (vf already in registers)
#pragma unroll
      for (int kc = 0; kc < 2; kc++) {
#pragma unroll
        for (int qm = 0; qm < 2; qm++) {
          short8 pf = *(const short8*)(Ppw + qm * 512 + lcol * 32 +
                                       (((kc * 4 + quad) ^ (lcol & 7)) << 2));
          __builtin_amdgcn_s_setprio(1);
#pragma unroll
          for (int nt = 0; nt < 4; nt++)
            O[qm][nt] = __builtin_amdgcn_mfma_f32_16x16x32_bf16(
                vf[kc][nt], pf, O[qm][nt], 0, 0, 0);
          __builtin_amdgcn_s_setprio(0);
        }
      }
    }

    // ---- write staged V (regs arrived during compute) into back buffer ----
    if (it < 15) {
      const ushort* a0 = (const ushort*)va;
      const ushort* a1 = (const ushort*)vb;
      ushort* Vtn = Vt[cb ^ 1];
#pragma unroll
      for (int i = 0; i < 16; i++) {
        int dim = dg * 16 + i;
        unsigned pack = (unsigned)a0[i] | ((unsigned)a1[i] << 16);
        int pch = (pl >> 2) ^ (dim & 7);
        *(unsigned*)(&Vtn[dim * 128 + pch * 8 + (pl & 3) * 2]) = pack;
      }
    }
    asm volatile("s_waitcnt vmcnt(0)" ::: "memory");  // belt-and-suspenders DMA drain
    __syncthreads();  // drains K-DMA (vmcnt) + Vt writes; flips buffers
    cb ^= 1;
  }

  // epilogue: O^T -> out. lane owns q=lcol, dims nt*16+quad*4+r (consecutive)
#pragma unroll
  for (int qm = 0; qm < 2; qm++) {
    float s = lsum[qm];
    s += __shfl_xor(s, 16, 64);
    s += __shfl_xor(s, 32, 64);
    float rl = 1.f / s;
#pragma unroll
    for (int nt = 0; nt < 4; nt++) {
      ushort4 o;
      o.x = f2bf(O[qm][nt][0] * rl);
      o.y = f2bf(O[qm][nt][1] * rl);
      o.z = f2bf(O[qm][nt][2] * rl);
      o.w = f2bf(O[qm][nt][3] * rl);
      *(ushort4*)(out + base + (size_t)(q0 + qm * 16 + lcol) * 512 +
                  nt * 16 + quad * 4) = o;
    }
  }
}

// ---------------------------------------------------------------------------
// layernorm over last dim (512), bf16 in; bf16 or fp32 out.
// ---------------------------------------------------------------------------
template <bool OUTF32>
__global__ __launch_bounds__(256) void ln_kernel(
    const ushort* __restrict__ h, const float* __restrict__ g,
    const float* __restrict__ beta, void* __restrict__ outv) {
  int wave = threadIdx.x >> 6, lane = threadIdx.x & 63;
  int row = blockIdx.x * 4 + wave;
  uint4 raw = *(const uint4*)(h + (size_t)row * 512 + lane * 8);
  const ushort* hu = (const ushort*)&raw;
  float vals[8];
#pragma unroll
  for (int i = 0; i < 8; i++) vals[i] = bf2f(hu[i]);
  float sum = 0.f;
#pragma unroll
  for (int i = 0; i < 8; i++) sum += vals[i];
#pragma unroll
  for (int off = 32; off >= 1; off >>= 1) sum += __shfl_xor(sum, off, 64);
  float mean = sum * (1.f / 512.f);
  float vs = 0.f;
#pragma unroll
  for (int i = 0; i < 8; i++) { float d = vals[i] - mean; vs += d * d; }
#pragma unroll
  for (int off = 32; off >= 1; off >>= 1) vs += __shfl_xor(vs, off, 64);
  float rstd = rsqrtf(vs * (1.f / 512.f) + 1e-5f);
  float4 gv0 = *(const float4*)(g + lane * 8);
  float4 gv1 = *(const float4*)(g + lane * 8 + 4);
  float4 bv0 = *(const float4*)(beta + lane * 8);
  float4 bv1 = *(const float4*)(beta + lane * 8 + 4);
  float gr[8] = {gv0.x, gv0.y, gv0.z, gv0.w, gv1.x, gv1.y, gv1.z, gv1.w};
  float br[8] = {bv0.x, bv0.y, bv0.z, bv0.w, bv1.x, bv1.y, bv1.z, bv1.w};
  float res[8];
#pragma unroll
  for (int i = 0; i < 8; i++) res[i] = (vals[i] - mean) * rstd * gr[i] + br[i];
  if (OUTF32) {
    float* op = (float*)outv + (size_t)row * 512 + lane * 8;
    float4 o0, o1;
    o0.x = res[0]; o0.y = res[1]; o0.z = res[2]; o0.w = res[3];
    o1.x = res[4]; o1.y = res[5]; o1.z = res[6]; o1.w = res[7];
    *(float4*)op = o0; *(float4*)(op + 4) = o1;
  } else {
    ushort* op = (ushort*)outv + (size_t)row * 512 + lane * 8;
    ushort4 o0, o1;
    o0.x = f2bf(res[0]); o0.y = f2bf(res[1]); o0.z = f2bf(res[2]); o0.w = f2bf(res[3]);
    o1.x = f2bf(res[4]); o1.y = f2bf(res[5]); o1.z = f2bf(res[6]); o1.w = f2bf(res[7]);
    *(ushort4*)op = o0; *(ushort4*)(op + 4) = o1;
  }
}

// ---------------------------------------------------------------------------
extern "C" void kernel_launch(void* const* d_in, const int* in_sizes, int n_in,
                              void* d_out, int out_size, void* d_ws,
                              size_t ws_size, hipStream_t stream) {
  (void)in_sizes; (void)n_in; (void)out_size; (void)ws_size;
  const float* x     = (const float*)d_in[0];
  const float* vis   = (const float*)d_in[1];
  const int*   c1    = (const int*)d_in[2];
  const int*   c2    = (const int*)d_in[3];
  const float* e1    = (const float*)d_in[4];
  const float* e2    = (const float*)d_in[5];
  const float* wq    = (const float*)d_in[6];
  const float* bq    = (const float*)d_in[7];
  const float* wk    = (const float*)d_in[8];
  const float* bk    = (const float*)d_in[9];
  const float* wv    = (const float*)d_in[10];
  const float* bv    = (const float*)d_in[11];
  const float* w1    = (const float*)d_in[12];
  const float* b1    = (const float*)d_in[13];
  const float* g1    = (const float*)d_in[14];
  const float* beta1 = (const float*)d_in[15];
  const float* w2    = (const float*)d_in[16];
  const float* b2    = (const float*)d_in[17];
  const float* g2    = (const float*)d_in[18];
  const float* beta2 = (const float*)d_in[19];
  float* out = (float*)d_out;
  ushort* ws = (ushort*)d_ws;

  const size_t BUF = (size_t)MROWS * 512;
  ushort* xp_bf  = ws;             // later h1
  ushort* vis_bf = ws + BUF;       // later attn_out
  ushort* q_bf   = ws + 2 * BUF;   // later ln1
  ushort* k_bf   = ws + 3 * BUF;   // later h2
  ushort* v_bf   = ws + 4 * BUF;
  ushort* wt_qkv = ws + 5 * BUF;
  ushort* wt1    = wt_qkv + 1536 * 512;
  ushort* wt2    = wt1 + 512 * 512;
  ushort* attn_bf = vis_bf;
  ushort* h1_bf   = xp_bf;
  ushort* ln1_bf  = q_bf;
  ushort* h2_bf   = k_bf;

  prep_wtrans_kernel<<<4416, 256, 0, stream>>>(
      x, vis, c1, c2, e1, e2, wq, wk, wv, w1, w2, xp_bf, vis_bf, wt_qkv, wt1, wt2);
  gemm_mfma<false><<<dim3(12, 128), 256, 0, stream>>>(
      vis_bf, xp_bf, wt_qkv, bq, bk, bv, q_bf, k_bf, v_bf, 0.125f * 1.44269504f);
  attn_mfma_kernel<<<512, 256, 0, stream>>>(q_bf, k_bf, v_bf, attn_bf);
  gemm_mfma<true><<<dim3(4, 128), 256, 0, stream>>>(
      attn_bf, attn_bf, wt1, b1, b1, b1, h1_bf, h1_bf, h1_bf, 1.0f);
  ln_kernel<false><<<2048, 256, 0, stream>>>(h1_bf, g1, beta1, ln1_bf);
  gemm_mfma<true><<<dim3(4, 128), 256, 0, stream>>>(
      ln1_bf, ln1_bf, wt2, b2, b2, b2, h2_bf, h2_bf, h2_bf, 1.0f);
  ln_kernel<true><<<2048, 256, 0, stream>>>(h2_bf, g2, beta2, out);
}

// Round 7
// 266.176 us; speedup vs baseline: 1.0388x; 1.0388x over previous
//
#include <hip/hip_runtime.h>

#define DIM 512
#define SEQ 2048
#define MROWS 8192

typedef short short8 __attribute__((ext_vector_type(8)));
typedef float floatx4 __attribute__((ext_vector_type(4)));

__device__ __forceinline__ ushort f2bf(float f) {
  union { float f; unsigned u; } v; v.f = f;
  unsigned r = v.u + 0x7fff + ((v.u >> 16) & 1);
  return (ushort)(r >> 16);
}
__device__ __forceinline__ float bf2f(ushort u) {
  union { unsigned u; float f; } v; v.u = ((unsigned)u) << 16;
  return v.f;
}

// ---------------------------------------------------------------------------
// prep (blocks 0..4095): vis->bf16, xp = x + concat(emb1[c1],emb2[c2]) -> bf16
// wtrans (blocks 4096..4415): Wt[n][k] = W[k][n] bf16.
// wq pre-scaled by 0.125*log2(e): QK^T yields S*log2e, softmax uses bare
// v_exp_f32 (exp2). exp2(s*log2e)=e^s.
// ---------------------------------------------------------------------------
__global__ __launch_bounds__(256) void prep_wtrans_kernel(
    const float* __restrict__ x, const float* __restrict__ vis,
    const int* __restrict__ c1, const int* __restrict__ c2,
    const float* __restrict__ e1, const float* __restrict__ e2,
    const float* __restrict__ wq, const float* __restrict__ wk,
    const float* __restrict__ wv, const float* __restrict__ w1,
    const float* __restrict__ w2,
    ushort* __restrict__ xp_bf, ushort* __restrict__ vis_bf,
    ushort* __restrict__ wt_qkv, ushort* __restrict__ wt1,
    ushort* __restrict__ wt2) {
  __shared__ float Ls[64 * 65];
  if (blockIdx.x < 4096) {
    int gid = blockIdx.x * 256 + threadIdx.x;
    int row = gid >> 7;
    int col = (gid & 127) * 4;
    float4 vv = *(const float4*)(vis + (size_t)row * 512 + col);
    ushort4 vb; vb.x = f2bf(vv.x); vb.y = f2bf(vv.y); vb.z = f2bf(vv.z); vb.w = f2bf(vv.w);
    *(ushort4*)(vis_bf + (size_t)row * 512 + col) = vb;
    float4 p;
    if (col < 256) p = *(const float4*)(e1 + (size_t)c1[row] * 256 + col);
    else           p = *(const float4*)(e2 + (size_t)c2[row] * 256 + col - 256);
    float4 xv = *(const float4*)(x + (size_t)row * 512 + col);
    ushort4 xb; xb.x = f2bf(xv.x + p.x); xb.y = f2bf(xv.y + p.y);
    xb.z = f2bf(xv.z + p.z); xb.w = f2bf(xv.w + p.w);
    *(ushort4*)(xp_bf + (size_t)row * 512 + col) = xb;
  } else {
    int bid = blockIdx.x - 4096;
    int mid = bid >> 6;
    int tile = bid & 63;
    int k0 = (tile >> 3) * 64, n0 = (tile & 7) * 64;
    const float* W = mid == 0 ? wq : mid == 1 ? wk : mid == 2 ? wv : mid == 3 ? w1 : w2;
    ushort* outp = mid < 3 ? (wt_qkv + (size_t)mid * 512 * 512) : (mid == 3 ? wt1 : wt2);
    float scale = (mid == 0) ? 0.125f * 1.44269504f : 1.0f;
    int r = threadIdx.x >> 4, c4 = (threadIdx.x & 15) * 4;
#pragma unroll
    for (int i = 0; i < 4; i++) {
      int row = i * 16 + r;
      float4 wv4 = *(const float4*)(W + (size_t)(k0 + row) * 512 + n0 + c4);
      Ls[row * 65 + c4 + 0] = wv4.x * scale;
      Ls[row * 65 + c4 + 1] = wv4.y * scale;
      Ls[row * 65 + c4 + 2] = wv4.z * scale;
      Ls[row * 65 + c4 + 3] = wv4.w * scale;
    }
    __syncthreads();
    int n = threadIdx.x >> 2, kc = (threadIdx.x & 3) * 16;
    ushort pk[16];
#pragma unroll
    for (int i = 0; i < 16; i++) pk[i] = f2bf(Ls[(kc + i) * 65 + n]);
    ushort* op = outp + (size_t)(n0 + n) * 512 + k0 + kc;
    *(uint4*)op = *(uint4*)pk;
    *(uint4*)(op + 8) = *(uint4*)(pk + 8);
  }
}

// ---------------------------------------------------------------------------
// bf16 MFMA GEMM, 64x128 (MxN) tile, BK=64, XOR-swizzled LDS via DMA
// (pre-swizzled global source, linear LDS dest).
// 2-phase double-buffered staging (T3 minimal recipe): prologue-stage,
// then per k-step {STAGE(next buf) -> compute(cur buf) -> vmcnt(0) ->
// barrier}. DMA latency hides under ds_read+MFMA instead of being fully
// exposed between two barriers. LDS 48 KB -> 3 blocks/CU.
// grid (nchunks, 128). seg = n>>9 selects A/bias/out (QKV fusion).
// ---------------------------------------------------------------------------
template <bool LEAKY>
__global__ __launch_bounds__(256, 4) void gemm_mfma(
    const ushort* __restrict__ A01, const ushort* __restrict__ A2,
    const ushort* __restrict__ Wt,
    const float* __restrict__ bias0, const float* __restrict__ bias1,
    const float* __restrict__ bias2,
    ushort* __restrict__ out0, ushort* __restrict__ out1,
    ushort* __restrict__ out2, float s0scale) {
  __shared__ __align__(16) ushort Sm[24576];  // 2 x (As 64x64 | Bs 128x64)
  int t = threadIdx.x;
  int seg = blockIdx.x >> 2;
  int nloc0 = (blockIdx.x & 3) * 128;
  int n0w = blockIdx.x * 128;
  int m0 = blockIdx.y * 64;
  const ushort* A = (seg < 2) ? A01 : A2;
  const float* bias = seg == 0 ? bias0 : seg == 1 ? bias1 : bias2;
  ushort* out = seg == 0 ? out0 : seg == 1 ? out1 : out2;
  float bscale = seg == 0 ? s0scale : 1.0f;

  int w = t >> 6, lane = t & 63;
  int wm = (w & 1) * 32, wn = (w >> 1) * 64;
  int quad = lane >> 4, lcol = lane & 15;
  int l8g = lane >> 3, l7g = lane & 7;
  int gchs = (l7g ^ l8g) * 8;  // pre-swizzled source chunk (ushorts)

  floatx4 acc[2][4] = {};

#define GEMM_STAGE(K0, BUF)                                                   \
  {                                                                           \
    ushort* As_ = Sm + (BUF) * 12288;                                         \
    ushort* Bs_ = As_ + 4096;                                                 \
    _Pragma("unroll") for (int i = 0; i < 2; i++) {                           \
      int r0 = w * 16 + i * 8;                                                \
      __builtin_amdgcn_global_load_lds(                                       \
          (const __attribute__((address_space(1))) unsigned*)(                \
              A + (size_t)(m0 + r0 + l8g) * 512 + (K0) + gchs),               \
          (__attribute__((address_space(3))) unsigned*)(&As_[r0 * 64]),       \
          16, 0, 0);                                                          \
    }                                                                         \
    _Pragma("unroll") for (int i = 0; i < 4; i++) {                           \
      int r0 = w * 32 + i * 8;                                                \
      __builtin_amdgcn_global_load_lds(                                       \
          (const __attribute__((address_space(1))) unsigned*)(                \
              Wt + (size_t)(n0w + r0 + l8g) * 512 + (K0) + gchs),             \
          (__attribute__((address_space(3))) unsigned*)(&Bs_[r0 * 64]),       \
          16, 0, 0);                                                          \
    }                                                                         \
  }

  // prologue: stage k-step 0
  GEMM_STAGE(0, 0);
  asm volatile("s_waitcnt vmcnt(0)" ::: "memory");
  __syncthreads();

  for (int ks = 0; ks < 8; ks++) {
    int cur = ks & 1;
    if (ks < 7) GEMM_STAGE((ks + 1) * 64, cur ^ 1);  // prefetch next
    const ushort* As = Sm + cur * 12288;
    const ushort* Bs = As + 4096;
#pragma unroll
    for (int kc = 0; kc < 2; kc++) {
      int pch = ((kc * 4 + quad) ^ (lcol & 7)) * 8;
      short8 af[2], bfr[4];
#pragma unroll
      for (int i = 0; i < 2; i++)
        af[i] = *(const short8*)(&As[(wm + i * 16 + lcol) * 64 + pch]);
#pragma unroll
      for (int i = 0; i < 4; i++)
        bfr[i] = *(const short8*)(&Bs[(wn + i * 16 + lcol) * 64 + pch]);
#pragma unroll
      for (int mt = 0; mt < 2; mt++)
#pragma unroll
        for (int nt = 0; nt < 4; nt++)
          acc[mt][nt] = __builtin_amdgcn_mfma_f32_16x16x32_bf16(
              af[mt], bfr[nt], acc[mt][nt], 0, 0, 0);
    }
    asm volatile("s_waitcnt vmcnt(0)" ::: "memory");  // next-buf DMA landed
    __syncthreads();
  }
#undef GEMM_STAGE

  // epilogue: wave-private LDS transpose -> coalesced 16B bf16 stores
  float* Ls = (float*)Sm + w * 1088;  // 16x68 f32 per wave
  int rr = lane >> 2, cc = (lane & 3) * 16;
#pragma unroll
  for (int mt = 0; mt < 2; mt++) {
#pragma unroll
    for (int nt = 0; nt < 4; nt++) {
      float bv = bias[nloc0 + wn + nt * 16 + lcol] * bscale;
#pragma unroll
      for (int r = 0; r < 4; r++) {
        float vv = acc[mt][nt][r] + bv;
        if (LEAKY) vv = vv >= 0.f ? vv : 0.2f * vv;
        Ls[(quad * 4 + r) * 68 + nt * 16 + lcol] = vv;
      }
    }
    asm volatile("s_waitcnt lgkmcnt(0)" ::: "memory");
    ushort pk[16];
#pragma unroll
    for (int i = 0; i < 16; i += 4) {
      float4 fv = *(const float4*)(&Ls[rr * 68 + cc + i]);
      pk[i] = f2bf(fv.x); pk[i + 1] = f2bf(fv.y);
      pk[i + 2] = f2bf(fv.z); pk[i + 3] = f2bf(fv.w);
    }
    ushort* op = out + (size_t)(m0 + wm + mt * 16 + rr) * 512 + nloc0 + wn + cc;
    *(uint4*)op = *(uint4*)pk;
    *(uint4*)(op + 8) = *(uint4*)(pk + 8);
    asm volatile("s_waitcnt lgkmcnt(0)" ::: "memory");
  }
}

// ---------------------------------------------------------------------------
// MFMA flash attention (round-2 VERIFIED structure + exp2f only):
// swapped QK^T (S^T = mfma(K,Q)), lane-local softmax, P^T via cvt_pk ->
// ds_write_b64. K staged via global_load_lds dbuf, V reg-staged write-late,
// ONE barrier per K-tile. vf reads stay AFTER the P lgkmcnt (round-5 hoist
// + sched_barrier regressed: VALUBusy 33->46, dur 65->77; reverted).
// LDS 80 KB -> 2 blocks/CU (grid 512 = exact residency).
// ---------------------------------------------------------------------------
__global__ __launch_bounds__(256, 2) void attn_mfma_kernel(
    const ushort* __restrict__ q, const ushort* __restrict__ k,
    const ushort* __restrict__ v, ushort* __restrict__ out) {
  __shared__ __align__(16) ushort Ks[2][128 * 64];   // 2 x 16 KB, dbuf
  __shared__ __align__(16) ushort Vt[2][64 * 128];   // 2 x 16 KB, dbuf
  __shared__ __align__(16) unsigned Pp[4096];        // 16 KB, wave-private P^T
  int t = threadIdx.x;
  int blk = blockIdx.x;
  // XCD-chunked swizzle (bijective bit-rotate on 512 blocks)
  blk = ((blk & 7) << 6) | (blk >> 3);
  int qt = blk & 15, h = (blk >> 4) & 7, b = blk >> 7;
  int wave = t >> 6, lane = t & 63, quad = lane >> 4, lcol = lane & 15;
  int q0 = qt * 128 + wave * 32;
  const size_t base = (size_t)b * SEQ * 512 + h * 64;

  short8 qf[2][2];
#pragma unroll
  for (int qm = 0; qm < 2; qm++)
#pragma unroll
    for (int kc = 0; kc < 2; kc++)
      qf[qm][kc] = *(const short8*)(
          q + base + (size_t)(q0 + qm * 16 + lcol) * 512 + kc * 32 + quad * 8);

  floatx4 O[2][4] = {};
  float lsum[2] = {0.f, 0.f};

  unsigned* Ppw = Pp + wave * 1024;
  int pl = t & 63, dg = t >> 6;           // V staging: rows 2pl,2pl+1 dims dg*16+
  int l8 = lane >> 3, l7 = lane & 7;
  int kchs = (l7 ^ l8) * 8;               // pre-swizzled K source chunk (ushorts)
  const ushort* vbase = v + base + (size_t)(2 * pl) * 512 + dg * 16;

  uint4 va[2], vb[2];

  // ---- prologue: stage tile 0 ----
#pragma unroll
  for (int j = 0; j < 4; j++) {
    const ushort* gp = k + base + (size_t)((wave * 4 + j) * 8 + l8) * 512 + kchs;
    __builtin_amdgcn_global_load_lds(
        (const __attribute__((address_space(1))) unsigned*)gp,
        (__attribute__((address_space(3))) unsigned*)(&Ks[0][(wave * 4 + j) * 512]),
        16, 0, 0);
  }
  va[0] = *(const uint4*)(vbase);       va[1] = *(const uint4*)(vbase + 8);
  vb[0] = *(const uint4*)(vbase + 512); vb[1] = *(const uint4*)(vbase + 520);
  {
    const ushort* a0 = (const ushort*)va;
    const ushort* a1 = (const ushort*)vb;
#pragma unroll
    for (int i = 0; i < 16; i++) {
      int dim = dg * 16 + i;
      unsigned pack = (unsigned)a0[i] | ((unsigned)a1[i] << 16);
      int pch = (pl >> 2) ^ (dim & 7);
      *(unsigned*)(&Vt[0][dim * 128 + pch * 8 + (pl & 3) * 2]) = pack;
    }
  }
  __syncthreads();

  int cb = 0;
  for (int it = 0; it < 16; it++) {
    // ---- issue next tile's loads early (T14): K via DMA, V into regs ----
    if (it < 15) {
      int ktn = (it + 1) * 128;
#pragma unroll
      for (int j = 0; j < 4; j++) {
        const ushort* gp =
            k + base + (size_t)(ktn + (wave * 4 + j) * 8 + l8) * 512 + kchs;
        __builtin_amdgcn_global_load_lds(
            (const __attribute__((address_space(1))) unsigned*)gp,
            (__attribute__((address_space(3))) unsigned*)(
                &Ks[cb ^ 1][(wave * 4 + j) * 512]),
            16, 0, 0);
      }
      const ushort* vr = vbase + (size_t)ktn * 512;
      va[0] = *(const uint4*)(vr);       va[1] = *(const uint4*)(vr + 8);
      vb[0] = *(const uint4*)(vr + 512); vb[1] = *(const uint4*)(vr + 520);
    }

    const ushort* Ksb = Ks[cb];
    const ushort* Vtb = Vt[cb];
#pragma unroll
    for (int half = 0; half < 2; half++) {
      // hoist the 8 K fragments for this 64-key half (reused across qm)
      short8 kf[2][4];
#pragma unroll
      for (int kc = 0; kc < 2; kc++) {
        int pch = ((kc * 4 + quad) ^ (lcol & 7)) * 8;
#pragma unroll
        for (int jt = 0; jt < 4; jt++)
          kf[kc][jt] =
              *(const short8*)(&Ksb[((half * 4 + jt) * 16 + lcol) * 64 + pch]);
      }
#pragma unroll
      for (int qm = 0; qm < 2; qm++) {
        floatx4 S[4] = {};
        __builtin_amdgcn_s_setprio(1);
#pragma unroll
        for (int kc = 0; kc < 2; kc++)
#pragma unroll
          for (int jt = 0; jt < 4; jt++)
            S[jt] = __builtin_amdgcn_mfma_f32_16x16x32_bf16(
                kf[kc][jt], qf[qm][kc], S[jt], 0, 0, 0);
        __builtin_amdgcn_s_setprio(0);
        // S^T: col=lane&15=q, row=quad*4+r=key. S pre-scaled by log2e ->
        // exp2f is a bare v_exp_f32.
#pragma unroll
        for (int jt = 0; jt < 4; jt++) {
          float e0 = exp2f(S[jt][0]);
          float e1 = exp2f(S[jt][1]);
          float e2 = exp2f(S[jt][2]);
          float e3 = exp2f(S[jt][3]);
          lsum[qm] += (e0 + e1) + (e2 + e3);
          unsigned p0, p1;
          asm("v_cvt_pk_bf16_f32 %0, %1, %2" : "=v"(p0) : "v"(e0), "v"(e1));
          asm("v_cvt_pk_bf16_f32 %0, %1, %2" : "=v"(p1) : "v"(e2), "v"(e3));
          // pair index p0base = jt*8 + quad*2 ; chunk-of-4 XOR swizzle on lcol
          int c0 = 2 * jt + (quad >> 1);
          uint2 pk2; pk2.x = p0; pk2.y = p1;
          *(uint2*)(Ppw + qm * 512 + lcol * 32 + ((c0 ^ (lcol & 7)) << 2) +
                    (quad & 1) * 2) = pk2;
        }
      }
      asm volatile("s_waitcnt lgkmcnt(0)" ::: "memory");
      // PV: O^T[d][q] += V^T * P^T
#pragma unroll
      for (int kc = 0; kc < 2; kc++) {
        short8 vf[4];
        int ch = half * 8 + kc * 4 + quad;
#pragma unroll
        for (int nt = 0; nt < 4; nt++)
          vf[nt] = *(const short8*)(
              &Vtb[(nt * 16 + lcol) * 128 + ((ch ^ (lcol & 7)) * 8)]);
#pragma unroll
        for (int qm = 0; qm < 2; qm++) {
          short8 pf = *(const short8*)(Ppw + qm * 512 + lcol * 32 +
                                       (((kc * 4 + quad) ^ (lcol & 7)) << 2));
          __builtin_amdgcn_s_setprio(1);
#pragma unroll
          for (int nt = 0; nt < 4; nt++)
            O[qm][nt] = __builtin_amdgcn_mfma_f32_16x16x32_bf16(
                vf[nt], pf, O[qm][nt], 0, 0, 0);
          __builtin_amdgcn_s_setprio(0);
        }
      }
    }

    // ---- write staged V (regs arrived during compute) into back buffer ----
    if (it < 15) {
      const ushort* a0 = (const ushort*)va;
      const ushort* a1 = (const ushort*)vb;
      ushort* Vtn = Vt[cb ^ 1];
#pragma unroll
      for (int i = 0; i < 16; i++) {
        int dim = dg * 16 + i;
        unsigned pack = (unsigned)a0[i] | ((unsigned)a1[i] << 16);
        int pch = (pl >> 2) ^ (dim & 7);
        *(unsigned*)(&Vtn[dim * 128 + pch * 8 + (pl & 3) * 2]) = pack;
      }
    }
    asm volatile("s_waitcnt vmcnt(0)" ::: "memory");  // DMA drain
    __syncthreads();  // + Vt writes; flips buffers
    cb ^= 1;
  }

  // epilogue: O^T -> out. lane owns q=lcol, dims nt*16+quad*4+r (consecutive)
#pragma unroll
  for (int qm = 0; qm < 2; qm++) {
    float s = lsum[qm];
    s += __shfl_xor(s, 16, 64);
    s += __shfl_xor(s, 32, 64);
    float rl = 1.f / s;
#pragma unroll
    for (int nt = 0; nt < 4; nt++) {
      ushort4 o;
      o.x = f2bf(O[qm][nt][0] * rl);
      o.y = f2bf(O[qm][nt][1] * rl);
      o.z = f2bf(O[qm][nt][2] * rl);
      o.w = f2bf(O[qm][nt][3] * rl);
      *(ushort4*)(out + base + (size_t)(q0 + qm * 16 + lcol) * 512 +
                  nt * 16 + quad * 4) = o;
    }
  }
}

// ---------------------------------------------------------------------------
// layernorm over last dim (512), bf16 in; bf16 or fp32 out.
// ---------------------------------------------------------------------------
template <bool OUTF32>
__global__ __launch_bounds__(256) void ln_kernel(
    const ushort* __restrict__ h, const float* __restrict__ g,
    const float* __restrict__ beta, void* __restrict__ outv) {
  int wave = threadIdx.x >> 6, lane = threadIdx.x & 63;
  int row = blockIdx.x * 4 + wave;
  uint4 raw = *(const uint4*)(h + (size_t)row * 512 + lane * 8);
  const ushort* hu = (const ushort*)&raw;
  float vals[8];
#pragma unroll
  for (int i = 0; i < 8; i++) vals[i] = bf2f(hu[i]);
  float sum = 0.f;
#pragma unroll
  for (int i = 0; i < 8; i++) sum += vals[i];
#pragma unroll
  for (int off = 32; off >= 1; off >>= 1) sum += __shfl_xor(sum, off, 64);
  float mean = sum * (1.f / 512.f);
  float vs = 0.f;
#pragma unroll
  for (int i = 0; i < 8; i++) { float d = vals[i] - mean; vs += d * d; }
#pragma unroll
  for (int off = 32; off >= 1; off >>= 1) vs += __shfl_xor(vs, off, 64);
  float rstd = rsqrtf(vs * (1.f / 512.f) + 1e-5f);
  float4 gv0 = *(const float4*)(g + lane * 8);
  float4 gv1 = *(const float4*)(g + lane * 8 + 4);
  float4 bv0 = *(const float4*)(beta + lane * 8);
  float4 bv1 = *(const float4*)(beta + lane * 8 + 4);
  float gr[8] = {gv0.x, gv0.y, gv0.z, gv0.w, gv1.x, gv1.y, gv1.z, gv1.w};
  float br[8] = {bv0.x, bv0.y, bv0.z, bv0.w, bv1.x, bv1.y, bv1.z, bv1.w};
  float res[8];
#pragma unroll
  for (int i = 0; i < 8; i++) res[i] = (vals[i] - mean) * rstd * gr[i] + br[i];
  if (OUTF32) {
    float* op = (float*)outv + (size_t)row * 512 + lane * 8;
    float4 o0, o1;
    o0.x = res[0]; o0.y = res[1]; o0.z = res[2]; o0.w = res[3];
    o1.x = res[4]; o1.y = res[5]; o1.z = res[6]; o1.w = res[7];
    *(float4*)op = o0; *(float4*)(op + 4) = o1;
  } else {
    ushort* op = (ushort*)outv + (size_t)row * 512 + lane * 8;
    ushort4 o0, o1;
    o0.x = f2bf(res[0]); o0.y = f2bf(res[1]); o0.z = f2bf(res[2]); o0.w = f2bf(res[3]);
    o1.x = f2bf(res[4]); o1.y = f2bf(res[5]); o1.z = f2bf(res[6]); o1.w = f2bf(res[7]);
    *(ushort4*)op = o0; *(ushort4*)(op + 4) = o1;
  }
}

// ---------------------------------------------------------------------------
extern "C" void kernel_launch(void* const* d_in, const int* in_sizes, int n_in,
                              void* d_out, int out_size, void* d_ws,
                              size_t ws_size, hipStream_t stream) {
  (void)in_sizes; (void)n_in; (void)out_size; (void)ws_size;
  const float* x     = (const float*)d_in[0];
  const float* vis   = (const float*)d_in[1];
  const int*   c1    = (const int*)d_in[2];
  const int*   c2    = (const int*)d_in[3];
  const float* e1    = (const float*)d_in[4];
  const float* e2    = (const float*)d_in[5];
  const float* wq    = (const float*)d_in[6];
  const float* bq    = (const float*)d_in[7];
  const float* wk    = (const float*)d_in[8];
  const float* bk    = (const float*)d_in[9];
  const float* wv    = (const float*)d_in[10];
  const float* bv    = (const float*)d_in[11];
  const float* w1    = (const float*)d_in[12];
  const float* b1    = (const float*)d_in[13];
  const float* g1    = (const float*)d_in[14];
  const float* beta1 = (const float*)d_in[15];
  const float* w2    = (const float*)d_in[16];
  const float* b2    = (const float*)d_in[17];
  const float* g2    = (const float*)d_in[18];
  const float* beta2 = (const float*)d_in[19];
  float* out = (float*)d_out;
  ushort* ws = (ushort*)d_ws;

  const size_t BUF = (size_t)MROWS * 512;
  ushort* xp_bf  = ws;             // later h1
  ushort* vis_bf = ws + BUF;       // later attn_out
  ushort* q_bf   = ws + 2 * BUF;   // later ln1
  ushort* k_bf   = ws + 3 * BUF;   // later h2
  ushort* v_bf   = ws + 4 * BUF;
  ushort* wt_qkv = ws + 5 * BUF;
  ushort* wt1    = wt_qkv + 1536 * 512;
  ushort* wt2    = wt1 + 512 * 512;
  ushort* attn_bf = vis_bf;
  ushort* h1_bf   = xp_bf;
  ushort* ln1_bf  = q_bf;
  ushort* h2_bf   = k_bf;

  prep_wtrans_kernel<<<4416, 256, 0, stream>>>(
      x, vis, c1, c2, e1, e2, wq, wk, wv, w1, w2, xp_bf, vis_bf, wt_qkv, wt1, wt2);
  gemm_mfma<false><<<dim3(12, 128), 256, 0, stream>>>(
      vis_bf, xp_bf, wt_qkv, bq, bk, bv, q_bf, k_bf, v_bf, 0.125f * 1.44269504f);
  attn_mfma_kernel<<<512, 256, 0, stream>>>(q_bf, k_bf, v_bf, attn_bf);
  gemm_mfma<true><<<dim3(4, 128), 256, 0, stream>>>(
      attn_bf, attn_bf, wt1, b1, b1, b1, h1_bf, h1_bf, h1_bf, 1.0f);
  ln_kernel<false><<<2048, 256, 0, stream>>>(h1_bf, g1, beta1, ln1_bf);
  gemm_mfma<true><<<dim3(4, 128), 256, 0, stream>>>(
      ln1_bf, ln1_bf, wt2, b2, b2, b2, h2_bf, h2_bf, h2_bf, 1.0f);
  ln_kernel<true><<<2048, 256, 0, stream>>>(h2_bf, g2, beta2, out);
}

// Round 8
// 258.295 us; speedup vs baseline: 1.0705x; 1.0305x over previous
//
#include <hip/hip_runtime.h>

#define DIM 512
#define SEQ 2048
#define MROWS 8192

typedef short short8 __attribute__((ext_vector_type(8)));
typedef float floatx4 __attribute__((ext_vector_type(4)));

__device__ __forceinline__ ushort f2bf(float f) {
  union { float f; unsigned u; } v; v.f = f;
  unsigned r = v.u + 0x7fff + ((v.u >> 16) & 1);
  return (ushort)(r >> 16);
}
__device__ __forceinline__ float bf2f(ushort u) {
  union { unsigned u; float f; } v; v.u = ((unsigned)u) << 16;
  return v.f;
}
// bare v_exp_f32 (2^x). exp2f() lowers to libm __ocml_exp2_f32 (slow path,
// +12pt VALUBusy measured r7); this emits the native instruction.
__device__ __forceinline__ float fast_exp2(float x) {
  float r;
  asm("v_exp_f32 %0, %1" : "=v"(r) : "v"(x));
  return r;
}

// ---------------------------------------------------------------------------
// prep (blocks 0..4095): vis->bf16, xp = x + concat(emb1[c1],emb2[c2]) -> bf16
// wtrans (blocks 4096..4415): Wt[n][k] = W[k][n] bf16.
// wq pre-scaled by 0.125*log2(e): QK^T yields S*log2e, softmax uses bare
// v_exp_f32 (exp2). exp2(s*log2e)=e^s.
// ---------------------------------------------------------------------------
__global__ __launch_bounds__(256) void prep_wtrans_kernel(
    const float* __restrict__ x, const float* __restrict__ vis,
    const int* __restrict__ c1, const int* __restrict__ c2,
    const float* __restrict__ e1, const float* __restrict__ e2,
    const float* __restrict__ wq, const float* __restrict__ wk,
    const float* __restrict__ wv, const float* __restrict__ w1,
    const float* __restrict__ w2,
    ushort* __restrict__ xp_bf, ushort* __restrict__ vis_bf,
    ushort* __restrict__ wt_qkv, ushort* __restrict__ wt1,
    ushort* __restrict__ wt2) {
  __shared__ float Ls[64 * 65];
  if (blockIdx.x < 4096) {
    int gid = blockIdx.x * 256 + threadIdx.x;
    int row = gid >> 7;
    int col = (gid & 127) * 4;
    float4 vv = *(const float4*)(vis + (size_t)row * 512 + col);
    ushort4 vb; vb.x = f2bf(vv.x); vb.y = f2bf(vv.y); vb.z = f2bf(vv.z); vb.w = f2bf(vv.w);
    *(ushort4*)(vis_bf + (size_t)row * 512 + col) = vb;
    float4 p;
    if (col < 256) p = *(const float4*)(e1 + (size_t)c1[row] * 256 + col);
    else           p = *(const float4*)(e2 + (size_t)c2[row] * 256 + col - 256);
    float4 xv = *(const float4*)(x + (size_t)row * 512 + col);
    ushort4 xb; xb.x = f2bf(xv.x + p.x); xb.y = f2bf(xv.y + p.y);
    xb.z = f2bf(xv.z + p.z); xb.w = f2bf(xv.w + p.w);
    *(ushort4*)(xp_bf + (size_t)row * 512 + col) = xb;
  } else {
    int bid = blockIdx.x - 4096;
    int mid = bid >> 6;
    int tile = bid & 63;
    int k0 = (tile >> 3) * 64, n0 = (tile & 7) * 64;
    const float* W = mid == 0 ? wq : mid == 1 ? wk : mid == 2 ? wv : mid == 3 ? w1 : w2;
    ushort* outp = mid < 3 ? (wt_qkv + (size_t)mid * 512 * 512) : (mid == 3 ? wt1 : wt2);
    float scale = (mid == 0) ? 0.125f * 1.44269504f : 1.0f;
    int r = threadIdx.x >> 4, c4 = (threadIdx.x & 15) * 4;
#pragma unroll
    for (int i = 0; i < 4; i++) {
      int row = i * 16 + r;
      float4 wv4 = *(const float4*)(W + (size_t)(k0 + row) * 512 + n0 + c4);
      Ls[row * 65 + c4 + 0] = wv4.x * scale;
      Ls[row * 65 + c4 + 1] = wv4.y * scale;
      Ls[row * 65 + c4 + 2] = wv4.z * scale;
      Ls[row * 65 + c4 + 3] = wv4.w * scale;
    }
    __syncthreads();
    int n = threadIdx.x >> 2, kc = (threadIdx.x & 3) * 16;
    ushort pk[16];
#pragma unroll
    for (int i = 0; i < 16; i++) pk[i] = f2bf(Ls[(kc + i) * 65 + n]);
    ushort* op = outp + (size_t)(n0 + n) * 512 + k0 + kc;
    *(uint4*)op = *(uint4*)pk;
    *(uint4*)(op + 8) = *(uint4*)(pk + 8);
  }
}

// ---------------------------------------------------------------------------
// bf16 MFMA GEMM, 64x128 (MxN) tile, BK=64, XOR-swizzled LDS via DMA
// (pre-swizzled global source, linear LDS dest).
// 2-phase double-buffered staging: prologue-stage, then per k-step
// {STAGE(next buf) -> compute(cur buf) -> vmcnt(0) -> barrier}.
// LDS 48 KB -> 3 blocks/CU. grid (nchunks, 128). seg selects A/bias/out.
// ---------------------------------------------------------------------------
template <bool LEAKY>
__global__ __launch_bounds__(256, 4) void gemm_mfma(
    const ushort* __restrict__ A01, const ushort* __restrict__ A2,
    const ushort* __restrict__ Wt,
    const float* __restrict__ bias0, const float* __restrict__ bias1,
    const float* __restrict__ bias2,
    ushort* __restrict__ out0, ushort* __restrict__ out1,
    ushort* __restrict__ out2, float s0scale) {
  __shared__ __align__(16) ushort Sm[24576];  // 2 x (As 64x64 | Bs 128x64)
  int t = threadIdx.x;
  int seg = blockIdx.x >> 2;
  int nloc0 = (blockIdx.x & 3) * 128;
  int n0w = blockIdx.x * 128;
  int m0 = blockIdx.y * 64;
  const ushort* A = (seg < 2) ? A01 : A2;
  const float* bias = seg == 0 ? bias0 : seg == 1 ? bias1 : bias2;
  ushort* out = seg == 0 ? out0 : seg == 1 ? out1 : out2;
  float bscale = seg == 0 ? s0scale : 1.0f;

  int w = t >> 6, lane = t & 63;
  int wm = (w & 1) * 32, wn = (w >> 1) * 64;
  int quad = lane >> 4, lcol = lane & 15;
  int l8g = lane >> 3, l7g = lane & 7;
  int gchs = (l7g ^ l8g) * 8;  // pre-swizzled source chunk (ushorts)

  floatx4 acc[2][4] = {};

#define GEMM_STAGE(K0, BUF)                                                   \
  {                                                                           \
    ushort* As_ = Sm + (BUF) * 12288;                                         \
    ushort* Bs_ = As_ + 4096;                                                 \
    _Pragma("unroll") for (int i = 0; i < 2; i++) {                           \
      int r0 = w * 16 + i * 8;                                                \
      __builtin_amdgcn_global_load_lds(                                       \
          (const __attribute__((address_space(1))) unsigned*)(                \
              A + (size_t)(m0 + r0 + l8g) * 512 + (K0) + gchs),               \
          (__attribute__((address_space(3))) unsigned*)(&As_[r0 * 64]),       \
          16, 0, 0);                                                          \
    }                                                                         \
    _Pragma("unroll") for (int i = 0; i < 4; i++) {                           \
      int r0 = w * 32 + i * 8;                                                \
      __builtin_amdgcn_global_load_lds(                                       \
          (const __attribute__((address_space(1))) unsigned*)(                \
              Wt + (size_t)(n0w + r0 + l8g) * 512 + (K0) + gchs),             \
          (__attribute__((address_space(3))) unsigned*)(&Bs_[r0 * 64]),       \
          16, 0, 0);                                                          \
    }                                                                         \
  }

  // prologue: stage k-step 0
  GEMM_STAGE(0, 0);
  asm volatile("s_waitcnt vmcnt(0)" ::: "memory");
  __syncthreads();

  for (int ks = 0; ks < 8; ks++) {
    int cur = ks & 1;
    if (ks < 7) GEMM_STAGE((ks + 1) * 64, cur ^ 1);  // prefetch next
    const ushort* As = Sm + cur * 12288;
    const ushort* Bs = As + 4096;
#pragma unroll
    for (int kc = 0; kc < 2; kc++) {
      int pch = ((kc * 4 + quad) ^ (lcol & 7)) * 8;
      short8 af[2], bfr[4];
#pragma unroll
      for (int i = 0; i < 2; i++)
        af[i] = *(const short8*)(&As[(wm + i * 16 + lcol) * 64 + pch]);
#pragma unroll
      for (int i = 0; i < 4; i++)
        bfr[i] = *(const short8*)(&Bs[(wn + i * 16 + lcol) * 64 + pch]);
#pragma unroll
      for (int mt = 0; mt < 2; mt++)
#pragma unroll
        for (int nt = 0; nt < 4; nt++)
          acc[mt][nt] = __builtin_amdgcn_mfma_f32_16x16x32_bf16(
              af[mt], bfr[nt], acc[mt][nt], 0, 0, 0);
    }
    asm volatile("s_waitcnt vmcnt(0)" ::: "memory");  // next-buf DMA landed
    __syncthreads();
  }
#undef GEMM_STAGE

  // epilogue: wave-private LDS transpose -> coalesced 16B bf16 stores
  float* Ls = (float*)Sm + w * 1088;  // 16x68 f32 per wave
  int rr = lane >> 2, cc = (lane & 3) * 16;
#pragma unroll
  for (int mt = 0; mt < 2; mt++) {
#pragma unroll
    for (int nt = 0; nt < 4; nt++) {
      float bv = bias[nloc0 + wn + nt * 16 + lcol] * bscale;
#pragma unroll
      for (int r = 0; r < 4; r++) {
        float vv = acc[mt][nt][r] + bv;
        if (LEAKY) vv = vv >= 0.f ? vv : 0.2f * vv;
        Ls[(quad * 4 + r) * 68 + nt * 16 + lcol] = vv;
      }
    }
    asm volatile("s_waitcnt lgkmcnt(0)" ::: "memory");
    ushort pk[16];
#pragma unroll
    for (int i = 0; i < 16; i += 4) {
      float4 fv = *(const float4*)(&Ls[rr * 68 + cc + i]);
      pk[i] = f2bf(fv.x); pk[i + 1] = f2bf(fv.y);
      pk[i + 2] = f2bf(fv.z); pk[i + 3] = f2bf(fv.w);
    }
    ushort* op = out + (size_t)(m0 + wm + mt * 16 + rr) * 512 + nloc0 + wn + cc;
    *(uint4*)op = *(uint4*)pk;
    *(uint4*)(op + 8) = *(uint4*)(pk + 8);
    asm volatile("s_waitcnt lgkmcnt(0)" ::: "memory");
  }
}

// ---------------------------------------------------------------------------
// MFMA flash attention (round-2 VERIFIED structure; softmax = bare v_exp_f32
// with log2e folded into wq). Swapped QK^T (S^T = mfma(K,Q)), lane-local
// softmax, P^T via cvt_pk -> ds_write_b64. K staged via global_load_lds dbuf,
// V reg-staged write-late, ONE barrier per K-tile.
// LDS 80 KB -> 2 blocks/CU (grid 512 = exact residency).
// ---------------------------------------------------------------------------
__global__ __launch_bounds__(256, 2) void attn_mfma_kernel(
    const ushort* __restrict__ q, const ushort* __restrict__ k,
    const ushort* __restrict__ v, ushort* __restrict__ out) {
  __shared__ __align__(16) ushort Ks[2][128 * 64];   // 2 x 16 KB, dbuf
  __shared__ __align__(16) ushort Vt[2][64 * 128];   // 2 x 16 KB, dbuf
  __shared__ __align__(16) unsigned Pp[4096];        // 16 KB, wave-private P^T
  int t = threadIdx.x;
  int blk = blockIdx.x;
  // XCD-chunked swizzle (bijective bit-rotate on 512 blocks)
  blk = ((blk & 7) << 6) | (blk >> 3);
  int qt = blk & 15, h = (blk >> 4) & 7, b = blk >> 7;
  int wave = t >> 6, lane = t & 63, quad = lane >> 4, lcol = lane & 15;
  int q0 = qt * 128 + wave * 32;
  const size_t base = (size_t)b * SEQ * 512 + h * 64;

  short8 qf[2][2];
#pragma unroll
  for (int qm = 0; qm < 2; qm++)
#pragma unroll
    for (int kc = 0; kc < 2; kc++)
      qf[qm][kc] = *(const short8*)(
          q + base + (size_t)(q0 + qm * 16 + lcol) * 512 + kc * 32 + quad * 8);

  floatx4 O[2][4] = {};
  float lsum[2] = {0.f, 0.f};

  unsigned* Ppw = Pp + wave * 1024;
  int pl = t & 63, dg = t >> 6;           // V staging: rows 2pl,2pl+1 dims dg*16+
  int l8 = lane >> 3, l7 = lane & 7;
  int kchs = (l7 ^ l8) * 8;               // pre-swizzled K source chunk (ushorts)
  const ushort* vbase = v + base + (size_t)(2 * pl) * 512 + dg * 16;

  uint4 va[2], vb[2];

  // ---- prologue: stage tile 0 ----
#pragma unroll
  for (int j = 0; j < 4; j++) {
    const ushort* gp = k + base + (size_t)((wave * 4 + j) * 8 + l8) * 512 + kchs;
    __builtin_amdgcn_global_load_lds(
        (const __attribute__((address_space(1))) unsigned*)gp,
        (__attribute__((address_space(3))) unsigned*)(&Ks[0][(wave * 4 + j) * 512]),
        16, 0, 0);
  }
  va[0] = *(const uint4*)(vbase);       va[1] = *(const uint4*)(vbase + 8);
  vb[0] = *(const uint4*)(vbase + 512); vb[1] = *(const uint4*)(vbase + 520);
  {
    const ushort* a0 = (const ushort*)va;
    const ushort* a1 = (const ushort*)vb;
#pragma unroll
    for (int i = 0; i < 16; i++) {
      int dim = dg * 16 + i;
      unsigned pack = (unsigned)a0[i] | ((unsigned)a1[i] << 16);
      int pch = (pl >> 2) ^ (dim & 7);
      *(unsigned*)(&Vt[0][dim * 128 + pch * 8 + (pl & 3) * 2]) = pack;
    }
  }
  __syncthreads();

  int cb = 0;
  for (int it = 0; it < 16; it++) {
    // ---- issue next tile's loads early (T14): K via DMA, V into regs ----
    if (it < 15) {
      int ktn = (it + 1) * 128;
#pragma unroll
      for (int j = 0; j < 4; j++) {
        const ushort* gp =
            k + base + (size_t)(ktn + (wave * 4 + j) * 8 + l8) * 512 + kchs;
        __builtin_amdgcn_global_load_lds(
            (const __attribute__((address_space(1))) unsigned*)gp,
            (__attribute__((address_space(3))) unsigned*)(
                &Ks[cb ^ 1][(wave * 4 + j) * 512]),
            16, 0, 0);
      }
      const ushort* vr = vbase + (size_t)ktn * 512;
      va[0] = *(const uint4*)(vr);       va[1] = *(const uint4*)(vr + 8);
      vb[0] = *(const uint4*)(vr + 512); vb[1] = *(const uint4*)(vr + 520);
    }

    const ushort* Ksb = Ks[cb];
    const ushort* Vtb = Vt[cb];
#pragma unroll
    for (int half = 0; half < 2; half++) {
      // hoist the 8 K fragments for this 64-key half (reused across qm)
      short8 kf[2][4];
#pragma unroll
      for (int kc = 0; kc < 2; kc++) {
        int pch = ((kc * 4 + quad) ^ (lcol & 7)) * 8;
#pragma unroll
        for (int jt = 0; jt < 4; jt++)
          kf[kc][jt] =
              *(const short8*)(&Ksb[((half * 4 + jt) * 16 + lcol) * 64 + pch]);
      }
#pragma unroll
      for (int qm = 0; qm < 2; qm++) {
        floatx4 S[4] = {};
        __builtin_amdgcn_s_setprio(1);
#pragma unroll
        for (int kc = 0; kc < 2; kc++)
#pragma unroll
          for (int jt = 0; jt < 4; jt++)
            S[jt] = __builtin_amdgcn_mfma_f32_16x16x32_bf16(
                kf[kc][jt], qf[qm][kc], S[jt], 0, 0, 0);
        __builtin_amdgcn_s_setprio(0);
        // S^T: col=lane&15=q, row=quad*4+r=key. S pre-scaled by log2e ->
        // bare v_exp_f32 via inline asm (exp2f lowers to slow libm, r7).
#pragma unroll
        for (int jt = 0; jt < 4; jt++) {
          float e0 = fast_exp2(S[jt][0]);
          float e1 = fast_exp2(S[jt][1]);
          float e2 = fast_exp2(S[jt][2]);
          float e3 = fast_exp2(S[jt][3]);
          lsum[qm] += (e0 + e1) + (e2 + e3);
          unsigned p0, p1;
          asm("v_cvt_pk_bf16_f32 %0, %1, %2" : "=v"(p0) : "v"(e0), "v"(e1));
          asm("v_cvt_pk_bf16_f32 %0, %1, %2" : "=v"(p1) : "v"(e2), "v"(e3));
          // pair index p0base = jt*8 + quad*2 ; chunk-of-4 XOR swizzle on lcol
          int c0 = 2 * jt + (quad >> 1);
          uint2 pk2; pk2.x = p0; pk2.y = p1;
          *(uint2*)(Ppw + qm * 512 + lcol * 32 + ((c0 ^ (lcol & 7)) << 2) +
                    (quad & 1) * 2) = pk2;
        }
      }
      asm volatile("s_waitcnt lgkmcnt(0)" ::: "memory");
      // PV: O^T[d][q] += V^T * P^T
#pragma unroll
      for (int kc = 0; kc < 2; kc++) {
        short8 vf[4];
        int ch = half * 8 + kc * 4 + quad;
#pragma unroll
        for (int nt = 0; nt < 4; nt++)
          vf[nt] = *(const short8*)(
              &Vtb[(nt * 16 + lcol) * 128 + ((ch ^ (lcol & 7)) * 8)]);
#pragma unroll
        for (int qm = 0; qm < 2; qm++) {
          short8 pf = *(const short8*)(Ppw + qm * 512 + lcol * 32 +
                                       (((kc * 4 + quad) ^ (lcol & 7)) << 2));
          __builtin_amdgcn_s_setprio(1);
#pragma unroll
          for (int nt = 0; nt < 4; nt++)
            O[qm][nt] = __builtin_amdgcn_mfma_f32_16x16x32_bf16(
                vf[nt], pf, O[qm][nt], 0, 0, 0);
          __builtin_amdgcn_s_setprio(0);
        }
      }
    }

    // ---- write staged V (regs arrived during compute) into back buffer ----
    if (it < 15) {
      const ushort* a0 = (const ushort*)va;
      const ushort* a1 = (const ushort*)vb;
      ushort* Vtn = Vt[cb ^ 1];
#pragma unroll
      for (int i = 0; i < 16; i++) {
        int dim = dg * 16 + i;
        unsigned pack = (unsigned)a0[i] | ((unsigned)a1[i] << 16);
        int pch = (pl >> 2) ^ (dim & 7);
        *(unsigned*)(&Vtn[dim * 128 + pch * 8 + (pl & 3) * 2]) = pack;
      }
    }
    asm volatile("s_waitcnt vmcnt(0)" ::: "memory");  // DMA drain
    __syncthreads();  // + Vt writes; flips buffers
    cb ^= 1;
  }

  // epilogue: O^T -> out. lane owns q=lcol, dims nt*16+quad*4+r (consecutive)
#pragma unroll
  for (int qm = 0; qm < 2; qm++) {
    float s = lsum[qm];
    s += __shfl_xor(s, 16, 64);
    s += __shfl_xor(s, 32, 64);
    float rl = 1.f / s;
#pragma unroll
    for (int nt = 0; nt < 4; nt++) {
      ushort4 o;
      o.x = f2bf(O[qm][nt][0] * rl);
      o.y = f2bf(O[qm][nt][1] * rl);
      o.z = f2bf(O[qm][nt][2] * rl);
      o.w = f2bf(O[qm][nt][3] * rl);
      *(ushort4*)(out + base + (size_t)(q0 + qm * 16 + lcol) * 512 +
                  nt * 16 + quad * 4) = o;
    }
  }
}

// ---------------------------------------------------------------------------
// layernorm over last dim (512), bf16 in; bf16 or fp32 out.
// ---------------------------------------------------------------------------
template <bool OUTF32>
__global__ __launch_bounds__(256) void ln_kernel(
    const ushort* __restrict__ h, const float* __restrict__ g,
    const float* __restrict__ beta, void* __restrict__ outv) {
  int wave = threadIdx.x >> 6, lane = threadIdx.x & 63;
  int row = blockIdx.x * 4 + wave;
  uint4 raw = *(const uint4*)(h + (size_t)row * 512 + lane * 8);
  const ushort* hu = (const ushort*)&raw;
  float vals[8];
#pragma unroll
  for (int i = 0; i < 8; i++) vals[i] = bf2f(hu[i]);
  float sum = 0.f;
#pragma unroll
  for (int i = 0; i < 8; i++) sum += vals[i];
#pragma unroll
  for (int off = 32; off >= 1; off >>= 1) sum += __shfl_xor(sum, off, 64);
  float mean = sum * (1.f / 512.f);
  float vs = 0.f;
#pragma unroll
  for (int i = 0; i < 8; i++) { float d = vals[i] - mean; vs += d * d; }
#pragma unroll
  for (int off = 32; off >= 1; off >>= 1) vs += __shfl_xor(vs, off, 64);
  float rstd = rsqrtf(vs * (1.f / 512.f) + 1e-5f);
  float4 gv0 = *(const float4*)(g + lane * 8);
  float4 gv1 = *(const float4*)(g + lane * 8 + 4);
  float4 bv0 = *(const float4*)(beta + lane * 8);
  float4 bv1 = *(const float4*)(beta + lane * 8 + 4);
  float gr[8] = {gv0.x, gv0.y, gv0.z, gv0.w, gv1.x, gv1.y, gv1.z, gv1.w};
  float br[8] = {bv0.x, bv0.y, bv0.z, bv0.w, bv1.x, bv1.y, bv1.z, bv1.w};
  float res[8];
#pragma unroll
  for (int i = 0; i < 8; i++) res[i] = (vals[i] - mean) * rstd * gr[i] + br[i];
  if (OUTF32) {
    float* op = (float*)outv + (size_t)row * 512 + lane * 8;
    float4 o0, o1;
    o0.x = res[0]; o0.y = res[1]; o0.z = res[2]; o0.w = res[3];
    o1.x = res[4]; o1.y = res[5]; o1.z = res[6]; o1.w = res[7];
    *(float4*)op = o0; *(float4*)(op + 4) = o1;
  } else {
    ushort* op = (ushort*)outv + (size_t)row * 512 + lane * 8;
    ushort4 o0, o1;
    o0.x = f2bf(res[0]); o0.y = f2bf(res[1]); o0.z = f2bf(res[2]); o0.w = f2bf(res[3]);
    o1.x = f2bf(res[4]); o1.y = f2bf(res[5]); o1.z = f2bf(res[6]); o1.w = f2bf(res[7]);
    *(ushort4*)op = o0; *(ushort4*)(op + 4) = o1;
  }
}

// ---------------------------------------------------------------------------
extern "C" void kernel_launch(void* const* d_in, const int* in_sizes, int n_in,
                              void* d_out, int out_size, void* d_ws,
                              size_t ws_size, hipStream_t stream) {
  (void)in_sizes; (void)n_in; (void)out_size; (void)ws_size;
  const float* x     = (const float*)d_in[0];
  const float* vis   = (const float*)d_in[1];
  const int*   c1    = (const int*)d_in[2];
  const int*   c2    = (const int*)d_in[3];
  const float* e1    = (const float*)d_in[4];
  const float* e2    = (const float*)d_in[5];
  const float* wq    = (const float*)d_in[6];
  const float* bq    = (const float*)d_in[7];
  const float* wk    = (const float*)d_in[8];
  const float* bk    = (const float*)d_in[9];
  const float* wv    = (const float*)d_in[10];
  const float* bv    = (const float*)d_in[11];
  const float* w1    = (const float*)d_in[12];
  const float* b1    = (const float*)d_in[13];
  const float* g1    = (const float*)d_in[14];
  const float* beta1 = (const float*)d_in[15];
  const float* w2    = (const float*)d_in[16];
  const float* b2    = (const float*)d_in[17];
  const float* g2    = (const float*)d_in[18];
  const float* beta2 = (const float*)d_in[19];
  float* out = (float*)d_out;
  ushort* ws = (ushort*)d_ws;

  const size_t BUF = (size_t)MROWS * 512;
  ushort* xp_bf  = ws;             // later h1
  ushort* vis_bf = ws + BUF;       // later attn_out
  ushort* q_bf   = ws + 2 * BUF;   // later ln1
  ushort* k_bf   = ws + 3 * BUF;   // later h2
  ushort* v_bf   = ws + 4 * BUF;
  ushort* wt_qkv = ws + 5 * BUF;
  ushort* wt1    = wt_qkv + 1536 * 512;
  ushort* wt2    = wt1 + 512 * 512;
  ushort* attn_bf = vis_bf;
  ushort* h1_bf   = xp_bf;
  ushort* ln1_bf  = q_bf;
  ushort* h2_bf   = k_bf;

  prep_wtrans_kernel<<<4416, 256, 0, stream>>>(
      x, vis, c1, c2, e1, e2, wq, wk, wv, w1, w2, xp_bf, vis_bf, wt_qkv, wt1, wt2);
  gemm_mfma<false><<<dim3(12, 128), 256, 0, stream>>>(
      vis_bf, xp_bf, wt_qkv, bq, bk, bv, q_bf, k_bf, v_bf, 0.125f * 1.44269504f);
  attn_mfma_kernel<<<512, 256, 0, stream>>>(q_bf, k_bf, v_bf, attn_bf);
  gemm_mfma<true><<<dim3(4, 128), 256, 0, stream>>>(
      attn_bf, attn_bf, wt1, b1, b1, b1, h1_bf, h1_bf, h1_bf, 1.0f);
  ln_kernel<false><<<2048, 256, 0, stream>>>(h1_bf, g1, beta1, ln1_bf);
  gemm_mfma<true><<<dim3(4, 128), 256, 0, stream>>>(
      ln1_bf, ln1_bf, wt2, b2, b2, b2, h2_bf, h2_bf, h2_bf, 1.0f);
  ln_kernel<true><<<2048, 256, 0, stream>>>(h2_bf, g2, beta2, out);
}

// Round 9
// 248.236 us; speedup vs baseline: 1.1139x; 1.0405x over previous
//
#include <hip/hip_runtime.h>

#define DIM 512
#define SEQ 2048
#define MROWS 8192

typedef short short8 __attribute__((ext_vector_type(8)));
typedef float floatx4 __attribute__((ext_vector_type(4)));

__device__ __forceinline__ ushort f2bf(float f) {
  union { float f; unsigned u; } v; v.f = f;
  unsigned r = v.u + 0x7fff + ((v.u >> 16) & 1);
  return (ushort)(r >> 16);
}
__device__ __forceinline__ float bf2f(ushort u) {
  union { unsigned u; float f; } v; v.u = ((unsigned)u) << 16;
  return v.f;
}
// bare v_exp_f32 (2^x). exp2f() lowers to libm __ocml_exp2_f32 (slow path,
// +12pt VALUBusy measured r7); this emits the native instruction.
__device__ __forceinline__ float fast_exp2(float x) {
  float r;
  asm("v_exp_f32 %0, %1" : "=v"(r) : "v"(x));
  return r;
}

// ---------------------------------------------------------------------------
// prep (blocks 0..4095): vis->bf16, xp = x + concat(emb1[c1],emb2[c2]) -> bf16
// wtrans (blocks 4096..4415): Wt[n][k] = W[k][n] bf16.
// wq pre-scaled by 0.125*log2(e): QK^T yields S*log2e, softmax uses bare
// v_exp_f32 (exp2). exp2(s*log2e)=e^s.
// ---------------------------------------------------------------------------
__global__ __launch_bounds__(256) void prep_wtrans_kernel(
    const float* __restrict__ x, const float* __restrict__ vis,
    const int* __restrict__ c1, const int* __restrict__ c2,
    const float* __restrict__ e1, const float* __restrict__ e2,
    const float* __restrict__ wq, const float* __restrict__ wk,
    const float* __restrict__ wv, const float* __restrict__ w1,
    const float* __restrict__ w2,
    ushort* __restrict__ xp_bf, ushort* __restrict__ vis_bf,
    ushort* __restrict__ wt_qkv, ushort* __restrict__ wt1,
    ushort* __restrict__ wt2) {
  __shared__ float Ls[64 * 65];
  if (blockIdx.x < 4096) {
    int gid = blockIdx.x * 256 + threadIdx.x;
    int row = gid >> 7;
    int col = (gid & 127) * 4;
    float4 vv = *(const float4*)(vis + (size_t)row * 512 + col);
    ushort4 vb; vb.x = f2bf(vv.x); vb.y = f2bf(vv.y); vb.z = f2bf(vv.z); vb.w = f2bf(vv.w);
    *(ushort4*)(vis_bf + (size_t)row * 512 + col) = vb;
    float4 p;
    if (col < 256) p = *(const float4*)(e1 + (size_t)c1[row] * 256 + col);
    else           p = *(const float4*)(e2 + (size_t)c2[row] * 256 + col - 256);
    float4 xv = *(const float4*)(x + (size_t)row * 512 + col);
    ushort4 xb; xb.x = f2bf(xv.x + p.x); xb.y = f2bf(xv.y + p.y);
    xb.z = f2bf(xv.z + p.z); xb.w = f2bf(xv.w + p.w);
    *(ushort4*)(xp_bf + (size_t)row * 512 + col) = xb;
  } else {
    int bid = blockIdx.x - 4096;
    int mid = bid >> 6;
    int tile = bid & 63;
    int k0 = (tile >> 3) * 64, n0 = (tile & 7) * 64;
    const float* W = mid == 0 ? wq : mid == 1 ? wk : mid == 2 ? wv : mid == 3 ? w1 : w2;
    ushort* outp = mid < 3 ? (wt_qkv + (size_t)mid * 512 * 512) : (mid == 3 ? wt1 : wt2);
    float scale = (mid == 0) ? 0.125f * 1.44269504f : 1.0f;
    int r = threadIdx.x >> 4, c4 = (threadIdx.x & 15) * 4;
#pragma unroll
    for (int i = 0; i < 4; i++) {
      int row = i * 16 + r;
      float4 wv4 = *(const float4*)(W + (size_t)(k0 + row) * 512 + n0 + c4);
      Ls[row * 65 + c4 + 0] = wv4.x * scale;
      Ls[row * 65 + c4 + 1] = wv4.y * scale;
      Ls[row * 65 + c4 + 2] = wv4.z * scale;
      Ls[row * 65 + c4 + 3] = wv4.w * scale;
    }
    __syncthreads();
    int n = threadIdx.x >> 2, kc = (threadIdx.x & 3) * 16;
    ushort pk[16];
#pragma unroll
    for (int i = 0; i < 16; i++) pk[i] = f2bf(Ls[(kc + i) * 65 + n]);
    ushort* op = outp + (size_t)(n0 + n) * 512 + k0 + kc;
    *(uint4*)op = *(uint4*)pk;
    *(uint4*)(op + 8) = *(uint4*)(pk + 8);
  }
}

// ---------------------------------------------------------------------------
// bf16 MFMA GEMM, 64x128 (MxN) tile, BK=64, XOR-swizzled LDS via DMA
// (pre-swizzled global source, linear LDS dest).
// 2-phase double-buffered staging: prologue-stage, then per k-step
// {STAGE(next buf) -> compute(cur buf) -> vmcnt(0) -> barrier}.
// LDS 48 KB -> 3 blocks/CU. grid (nchunks, 128). seg selects A/bias/out.
// ---------------------------------------------------------------------------
template <bool LEAKY>
__global__ __launch_bounds__(256, 4) void gemm_mfma(
    const ushort* __restrict__ A01, const ushort* __restrict__ A2,
    const ushort* __restrict__ Wt,
    const float* __restrict__ bias0, const float* __restrict__ bias1,
    const float* __restrict__ bias2,
    ushort* __restrict__ out0, ushort* __restrict__ out1,
    ushort* __restrict__ out2, float s0scale) {
  __shared__ __align__(16) ushort Sm[24576];  // 2 x (As 64x64 | Bs 128x64)
  int t = threadIdx.x;
  int seg = blockIdx.x >> 2;
  int nloc0 = (blockIdx.x & 3) * 128;
  int n0w = blockIdx.x * 128;
  int m0 = blockIdx.y * 64;
  const ushort* A = (seg < 2) ? A01 : A2;
  const float* bias = seg == 0 ? bias0 : seg == 1 ? bias1 : bias2;
  ushort* out = seg == 0 ? out0 : seg == 1 ? out1 : out2;
  float bscale = seg == 0 ? s0scale : 1.0f;

  int w = t >> 6, lane = t & 63;
  int wm = (w & 1) * 32, wn = (w >> 1) * 64;
  int quad = lane >> 4, lcol = lane & 15;
  int l8g = lane >> 3, l7g = lane & 7;
  int gchs = (l7g ^ l8g) * 8;  // pre-swizzled source chunk (ushorts)

  floatx4 acc[2][4] = {};

#define GEMM_STAGE(K0, BUF)                                                   \
  {                                                                           \
    ushort* As_ = Sm + (BUF) * 12288;                                         \
    ushort* Bs_ = As_ + 4096;                                                 \
    _Pragma("unroll") for (int i = 0; i < 2; i++) {                           \
      int r0 = w * 16 + i * 8;                                                \
      __builtin_amdgcn_global_load_lds(                                       \
          (const __attribute__((address_space(1))) unsigned*)(                \
              A + (size_t)(m0 + r0 + l8g) * 512 + (K0) + gchs),               \
          (__attribute__((address_space(3))) unsigned*)(&As_[r0 * 64]),       \
          16, 0, 0);                                                          \
    }                                                                         \
    _Pragma("unroll") for (int i = 0; i < 4; i++) {                           \
      int r0 = w * 32 + i * 8;                                                \
      __builtin_amdgcn_global_load_lds(                                       \
          (const __attribute__((address_space(1))) unsigned*)(                \
              Wt + (size_t)(n0w + r0 + l8g) * 512 + (K0) + gchs),             \
          (__attribute__((address_space(3))) unsigned*)(&Bs_[r0 * 64]),       \
          16, 0, 0);                                                          \
    }                                                                         \
  }

  // prologue: stage k-step 0
  GEMM_STAGE(0, 0);
  asm volatile("s_waitcnt vmcnt(0)" ::: "memory");
  __syncthreads();

  for (int ks = 0; ks < 8; ks++) {
    int cur = ks & 1;
    if (ks < 7) GEMM_STAGE((ks + 1) * 64, cur ^ 1);  // prefetch next
    const ushort* As = Sm + cur * 12288;
    const ushort* Bs = As + 4096;
#pragma unroll
    for (int kc = 0; kc < 2; kc++) {
      int pch = ((kc * 4 + quad) ^ (lcol & 7)) * 8;
      short8 af[2], bfr[4];
#pragma unroll
      for (int i = 0; i < 2; i++)
        af[i] = *(const short8*)(&As[(wm + i * 16 + lcol) * 64 + pch]);
#pragma unroll
      for (int i = 0; i < 4; i++)
        bfr[i] = *(const short8*)(&Bs[(wn + i * 16 + lcol) * 64 + pch]);
#pragma unroll
      for (int mt = 0; mt < 2; mt++)
#pragma unroll
        for (int nt = 0; nt < 4; nt++)
          acc[mt][nt] = __builtin_amdgcn_mfma_f32_16x16x32_bf16(
              af[mt], bfr[nt], acc[mt][nt], 0, 0, 0);
    }
    asm volatile("s_waitcnt vmcnt(0)" ::: "memory");  // next-buf DMA landed
    __syncthreads();
  }
#undef GEMM_STAGE

  // epilogue: wave-private LDS transpose -> coalesced 16B bf16 stores
  float* Ls = (float*)Sm + w * 1088;  // 16x68 f32 per wave
  int rr = lane >> 2, cc = (lane & 3) * 16;
#pragma unroll
  for (int mt = 0; mt < 2; mt++) {
#pragma unroll
    for (int nt = 0; nt < 4; nt++) {
      float bv = bias[nloc0 + wn + nt * 16 + lcol] * bscale;
#pragma unroll
      for (int r = 0; r < 4; r++) {
        float vv = acc[mt][nt][r] + bv;
        if (LEAKY) vv = vv >= 0.f ? vv : 0.2f * vv;
        Ls[(quad * 4 + r) * 68 + nt * 16 + lcol] = vv;
      }
    }
    asm volatile("s_waitcnt lgkmcnt(0)" ::: "memory");
    ushort pk[16];
#pragma unroll
    for (int i = 0; i < 16; i += 4) {
      float4 fv = *(const float4*)(&Ls[rr * 68 + cc + i]);
      pk[i] = f2bf(fv.x); pk[i + 1] = f2bf(fv.y);
      pk[i + 2] = f2bf(fv.z); pk[i + 3] = f2bf(fv.w);
    }
    ushort* op = out + (size_t)(m0 + wm + mt * 16 + rr) * 512 + nloc0 + wn + cc;
    *(uint4*)op = *(uint4*)pk;
    *(uint4*)(op + 8) = *(uint4*)(pk + 8);
    asm volatile("s_waitcnt lgkmcnt(0)" ::: "memory");
  }
}

// ---------------------------------------------------------------------------
// MFMA flash attention v4: r8-verified math scaled to 4 blocks/CU.
// 64 q-rows/block (4 waves x 16 q), K-tile 64, grid 1024.
// CONTROLLED CHANGE vs failed v3: K staging is REG-BASED (issue-early,
// ds_write-late, identical swizzled addresses) -- no global_load_lds DMA
// anywhere, isolating the DMA x geometry interaction. V staging, P path
// (swapped QK^T, lane-local softmax, cvt_pk -> b64 swizzled), fragment
// math, fast_exp2, epilogue all carried from the passing r8 kernel (1 qm).
// LDS = Ks 2x8K + Vt 2x8K + Pp 8K = 40 KB -> 4 blocks/CU = 4 waves/SIMD
// (2x the r8 kernel's 2/SIMD latency-bound regime).
// ---------------------------------------------------------------------------
__global__ __launch_bounds__(256, 4) void attn_mfma_kernel(
    const ushort* __restrict__ q, const ushort* __restrict__ k,
    const ushort* __restrict__ v, ushort* __restrict__ out) {
  __shared__ __align__(16) ushort Ks[2][64 * 64];   // 2 x 8 KB, dbuf
  __shared__ __align__(16) ushort Vt[2][64 * 64];   // 2 x 8 KB, dbuf
  __shared__ __align__(16) unsigned Pp[2048];       // 8 KB, wave-private P^T
  int t = threadIdx.x;
  int blk = blockIdx.x;
  // bijective rotate on 1024 blocks: 128 consecutive logical blocks
  // (4 heads of K/V = 2 MB) per XCD L2
  blk = ((blk & 7) << 7) | (blk >> 3);
  int qt = blk & 31, h = (blk >> 5) & 7, b = blk >> 8;
  int wave = t >> 6, lane = t & 63, quad = lane >> 4, lcol = lane & 15;
  int q0 = qt * 64 + wave * 16;
  const size_t base = (size_t)b * SEQ * 512 + h * 64;

  short8 qf[2];
#pragma unroll
  for (int kc = 0; kc < 2; kc++)
    qf[kc] = *(const short8*)(
        q + base + (size_t)(q0 + lcol) * 512 + kc * 32 + quad * 8);

  floatx4 O[4] = {};
  float lsum = 0.f;

  unsigned* Ppw = Pp + wave * 512;
  int l8 = lane >> 3, l7 = lane & 7;
  int kchs = (l7 ^ l8) * 8;          // pre-swizzled K source chunk (ushorts)
  int krow = wave * 8 + l8;          // this thread's K rows: krow, krow+32
  int vp = t & 31, vdg = t >> 5;     // V staging: keys 2vp,2vp+1; dims vdg*8..+7
  const ushort* vbase = v + base + (size_t)(2 * vp) * 512 + vdg * 8;

  uint4 ka0, ka1, va, vb;

  // ---- prologue: stage tile 0 (reg -> LDS) ----
  ka0 = *(const uint4*)(k + base + (size_t)krow * 512 + kchs);
  ka1 = *(const uint4*)(k + base + (size_t)(krow + 32) * 512 + kchs);
  va = *(const uint4*)vbase;
  vb = *(const uint4*)(vbase + 512);
  *(uint4*)(&Ks[0][krow * 64 + l7 * 8]) = ka0;
  *(uint4*)(&Ks[0][(krow + 32) * 64 + l7 * 8]) = ka1;
  {
    const ushort* a0 = (const ushort*)&va;
    const ushort* a1 = (const ushort*)&vb;
#pragma unroll
    for (int i = 0; i < 8; i++) {
      int dim = vdg * 8 + i;
      unsigned pack = (unsigned)a0[i] | ((unsigned)a1[i] << 16);
      *(unsigned*)(&Vt[0][dim * 64 + ((vp >> 2) ^ (dim & 7)) * 8 +
                          (vp & 3) * 2]) = pack;
    }
  }
  __syncthreads();

  int cb = 0;
  for (int it = 0; it < 32; it++) {
    // ---- issue next tile's global loads early (T14) ----
    if (it < 31) {
      int ktn = (it + 1) * 64;
      ka0 = *(const uint4*)(k + base + (size_t)(ktn + krow) * 512 + kchs);
      ka1 = *(const uint4*)(k + base + (size_t)(ktn + krow + 32) * 512 + kchs);
      const ushort* vr = vbase + (size_t)ktn * 512;
      va = *(const uint4*)vr;
      vb = *(const uint4*)(vr + 512);
    }

    const ushort* Ksb = Ks[cb];
    const ushort* Vtb = Vt[cb];

    // QK^T (swapped): S^T = mfma(K, Q); lane holds S[key=jt*16+quad*4+r][q=lcol]
    short8 kf[2][4];
#pragma unroll
    for (int kc = 0; kc < 2; kc++) {
      int pch = ((kc * 4 + quad) ^ l7) * 8;
#pragma unroll
      for (int jt = 0; jt < 4; jt++)
        kf[kc][jt] = *(const short8*)(&Ksb[(jt * 16 + lcol) * 64 + pch]);
    }
    floatx4 S[4] = {};
    __builtin_amdgcn_s_setprio(1);
#pragma unroll
    for (int kc = 0; kc < 2; kc++)
#pragma unroll
      for (int jt = 0; jt < 4; jt++)
        S[jt] = __builtin_amdgcn_mfma_f32_16x16x32_bf16(
            kf[kc][jt], qf[kc], S[jt], 0, 0, 0);
    __builtin_amdgcn_s_setprio(0);

    // softmax (static max, S pre-scaled by log2e) + P^T pack -> swizzled b64
#pragma unroll
    for (int jt = 0; jt < 4; jt++) {
      float e0 = fast_exp2(S[jt][0]);
      float e1 = fast_exp2(S[jt][1]);
      float e2 = fast_exp2(S[jt][2]);
      float e3 = fast_exp2(S[jt][3]);
      lsum += (e0 + e1) + (e2 + e3);
      unsigned p0, p1;
      asm("v_cvt_pk_bf16_f32 %0, %1, %2" : "=v"(p0) : "v"(e0), "v"(e1));
      asm("v_cvt_pk_bf16_f32 %0, %1, %2" : "=v"(p1) : "v"(e2), "v"(e3));
      int c0 = 2 * jt + (quad >> 1);
      uint2 pk2; pk2.x = p0; pk2.y = p1;
      *(uint2*)(Ppw + lcol * 32 + ((c0 ^ l7) << 2) + (quad & 1) * 2) = pk2;
    }
    asm volatile("s_waitcnt lgkmcnt(0)" ::: "memory");

    // PV: O^T[d][q] += V^T * P^T (reads after the P-wait, r8-verified order)
#pragma unroll
    for (int kc = 0; kc < 2; kc++) {
      short8 vf[4];
      int ch = ((kc * 4 + quad) ^ l7) * 8;
#pragma unroll
      for (int nt = 0; nt < 4; nt++)
        vf[nt] = *(const short8*)(&Vtb[(nt * 16 + lcol) * 64 + ch]);
      short8 pf = *(const short8*)(Ppw + lcol * 32 +
                                   (((kc * 4 + quad) ^ l7) << 2));
      __builtin_amdgcn_s_setprio(1);
#pragma unroll
      for (int nt = 0; nt < 4; nt++)
        O[nt] = __builtin_amdgcn_mfma_f32_16x16x32_bf16(
            vf[nt], pf, O[nt], 0, 0, 0);
      __builtin_amdgcn_s_setprio(0);
    }

    // ---- write staged K/V (regs arrived during compute) into back buffer ----
    if (it < 31) {
      ushort* Ksn = Ks[cb ^ 1];
      *(uint4*)(&Ksn[krow * 64 + l7 * 8]) = ka0;
      *(uint4*)(&Ksn[(krow + 32) * 64 + l7 * 8]) = ka1;
      const ushort* a0 = (const ushort*)&va;
      const ushort* a1 = (const ushort*)&vb;
      ushort* Vtn = Vt[cb ^ 1];
#pragma unroll
      for (int i = 0; i < 8; i++) {
        int dim = vdg * 8 + i;
        unsigned pack = (unsigned)a0[i] | ((unsigned)a1[i] << 16);
        *(unsigned*)(&Vtn[dim * 64 + ((vp >> 2) ^ (dim & 7)) * 8 +
                          (vp & 3) * 2]) = pack;
      }
    }
    __syncthreads();  // publishes back buffer; flips
    cb ^= 1;
  }

  // epilogue: O^T -> out. lane owns q=lcol, dims nt*16+quad*4+r (consecutive)
  lsum += __shfl_xor(lsum, 16, 64);
  lsum += __shfl_xor(lsum, 32, 64);
  float rl = 1.f / lsum;
#pragma unroll
  for (int nt = 0; nt < 4; nt++) {
    ushort4 o;
    o.x = f2bf(O[nt][0] * rl);
    o.y = f2bf(O[nt][1] * rl);
    o.z = f2bf(O[nt][2] * rl);
    o.w = f2bf(O[nt][3] * rl);
    *(ushort4*)(out + base + (size_t)(q0 + lcol) * 512 + nt * 16 + quad * 4) = o;
  }
}

// ---------------------------------------------------------------------------
// layernorm over last dim (512), bf16 in; bf16 or fp32 out.
// ---------------------------------------------------------------------------
template <bool OUTF32>
__global__ __launch_bounds__(256) void ln_kernel(
    const ushort* __restrict__ h, const float* __restrict__ g,
    const float* __restrict__ beta, void* __restrict__ outv) {
  int wave = threadIdx.x >> 6, lane = threadIdx.x & 63;
  int row = blockIdx.x * 4 + wave;
  uint4 raw = *(const uint4*)(h + (size_t)row * 512 + lane * 8);
  const ushort* hu = (const ushort*)&raw;
  float vals[8];
#pragma unroll
  for (int i = 0; i < 8; i++) vals[i] = bf2f(hu[i]);
  float sum = 0.f;
#pragma unroll
  for (int i = 0; i < 8; i++) sum += vals[i];
#pragma unroll
  for (int off = 32; off >= 1; off >>= 1) sum += __shfl_xor(sum, off, 64);
  float mean = sum * (1.f / 512.f);
  float vs = 0.f;
#pragma unroll
  for (int i = 0; i < 8; i++) { float d = vals[i] - mean; vs += d * d; }
#pragma unroll
  for (int off = 32; off >= 1; off >>= 1) vs += __shfl_xor(vs, off, 64);
  float rstd = rsqrtf(vs * (1.f / 512.f) + 1e-5f);
  float4 gv0 = *(const float4*)(g + lane * 8);
  float4 gv1 = *(const float4*)(g + lane * 8 + 4);
  float4 bv0 = *(const float4*)(beta + lane * 8);
  float4 bv1 = *(const float4*)(beta + lane * 8 + 4);
  float gr[8] = {gv0.x, gv0.y, gv0.z, gv0.w, gv1.x, gv1.y, gv1.z, gv1.w};
  float br[8] = {bv0.x, bv0.y, bv0.z, bv0.w, bv1.x, bv1.y, bv1.z, bv1.w};
  float res[8];
#pragma unroll
  for (int i = 0; i < 8; i++) res[i] = (vals[i] - mean) * rstd * gr[i] + br[i];
  if (OUTF32) {
    float* op = (float*)outv + (size_t)row * 512 + lane * 8;
    float4 o0, o1;
    o0.x = res[0]; o0.y = res[1]; o0.z = res[2]; o0.w = res[3];
    o1.x = res[4]; o1.y = res[5]; o1.z = res[6]; o1.w = res[7];
    *(float4*)op = o0; *(float4*)(op + 4) = o1;
  } else {
    ushort* op = (ushort*)outv + (size_t)row * 512 + lane * 8;
    ushort4 o0, o1;
    o0.x = f2bf(res[0]); o0.y = f2bf(res[1]); o0.z = f2bf(res[2]); o0.w = f2bf(res[3]);
    o1.x = f2bf(res[4]); o1.y = f2bf(res[5]); o1.z = f2bf(res[6]); o1.w = f2bf(res[7]);
    *(ushort4*)op = o0; *(ushort4*)(op + 4) = o1;
  }
}

// ---------------------------------------------------------------------------
extern "C" void kernel_launch(void* const* d_in, const int* in_sizes, int n_in,
                              void* d_out, int out_size, void* d_ws,
                              size_t ws_size, hipStream_t stream) {
  (void)in_sizes; (void)n_in; (void)out_size; (void)ws_size;
  const float* x     = (const float*)d_in[0];
  const float* vis   = (const float*)d_in[1];
  const int*   c1    = (const int*)d_in[2];
  const int*   c2    = (const int*)d_in[3];
  const float* e1    = (const float*)d_in[4];
  const float* e2    = (const float*)d_in[5];
  const float* wq    = (const float*)d_in[6];
  const float* bq    = (const float*)d_in[7];
  const float* wk    = (const float*)d_in[8];
  const float* bk    = (const float*)d_in[9];
  const float* wv    = (const float*)d_in[10];
  const float* bv    = (const float*)d_in[11];
  const float* w1    = (const float*)d_in[12];
  const float* b1    = (const float*)d_in[13];
  const float* g1    = (const float*)d_in[14];
  const float* beta1 = (const float*)d_in[15];
  const float* w2    = (const float*)d_in[16];
  const float* b2    = (const float*)d_in[17];
  const float* g2    = (const float*)d_in[18];
  const float* beta2 = (const float*)d_in[19];
  float* out = (float*)d_out;
  ushort* ws = (ushort*)d_ws;

  const size_t BUF = (size_t)MROWS * 512;
  ushort* xp_bf  = ws;             // later h1
  ushort* vis_bf = ws + BUF;       // later attn_out
  ushort* q_bf   = ws + 2 * BUF;   // later ln1
  ushort* k_bf   = ws + 3 * BUF;   // later h2
  ushort* v_bf   = ws + 4 * BUF;
  ushort* wt_qkv = ws + 5 * BUF;
  ushort* wt1    = wt_qkv + 1536 * 512;
  ushort* wt2    = wt1 + 512 * 512;
  ushort* attn_bf = vis_bf;
  ushort* h1_bf   = xp_bf;
  ushort* ln1_bf  = q_bf;
  ushort* h2_bf   = k_bf;

  prep_wtrans_kernel<<<4416, 256, 0, stream>>>(
      x, vis, c1, c2, e1, e2, wq, wk, wv, w1, w2, xp_bf, vis_bf, wt_qkv, wt1, wt2);
  gemm_mfma<false><<<dim3(12, 128), 256, 0, stream>>>(
      vis_bf, xp_bf, wt_qkv, bq, bk, bv, q_bf, k_bf, v_bf, 0.125f * 1.44269504f);
  attn_mfma_kernel<<<1024, 256, 0, stream>>>(q_bf, k_bf, v_bf, attn_bf);
  gemm_mfma<true><<<dim3(4, 128), 256, 0, stream>>>(
      attn_bf, attn_bf, wt1, b1, b1, b1, h1_bf, h1_bf, h1_bf, 1.0f);
  ln_kernel<false><<<2048, 256, 0, stream>>>(h1_bf, g1, beta1, ln1_bf);
  gemm_mfma<true><<<dim3(4, 128), 256, 0, stream>>>(
      ln1_bf, ln1_bf, wt2, b2, b2, b2, h2_bf, h2_bf, h2_bf, 1.0f);
  ln_kernel<true><<<2048, 256, 0, stream>>>(h2_bf, g2, beta2, out);
}